// Round 1
// baseline (838.946 us; speedup 1.0000x reference)
//
#include <hip/hip_runtime.h>
#include <hip/hip_bf16.h>
#include <math.h>

// Problem constants (fixed by reference): N=100000 nodes, E=1.6M edges, H=256, T=64.

static inline size_t align512(size_t x){ return (x + 511) & ~size_t(511); }

typedef _Float16 h2_t __attribute__((ext_vector_type(2)));
typedef unsigned short ushort_t;
typedef short bf16x8 __attribute__((ext_vector_type(8)));   // 8 bf16 = 4 VGPRs (MFMA A/B frag)
typedef float f32x4 __attribute__((ext_vector_type(4)));    // MFMA C/D frag
typedef float f32x2 __attribute__((ext_vector_type(2)));

#if defined(__has_builtin)
#if __has_builtin(__builtin_amdgcn_fdot2)
#define HAS_FDOT2 1
#endif
#if __has_builtin(__builtin_amdgcn_cvt_pk_f32_fp8) && __has_builtin(__builtin_amdgcn_cvt_pk_fp8_f32)
#define HAS_FP8CVT 1
#endif
#endif

__device__ inline ushort_t f2bf(float f){
  unsigned u = __float_as_uint(f);
  unsigned r = u + 0x7FFFu + ((u >> 16) & 1u);   // RTNE
  return (ushort_t)(r >> 16);
}
__device__ inline float bf2f(ushort_t h){ return __uint_as_float(((unsigned)h) << 16); }
__device__ inline unsigned pk2bf(float lo, float hi){
  return ((unsigned)f2bf(hi) << 16) | (unsigned)f2bf(lo);
}
__device__ inline bf16x8 as_bf16x8(uint4 u){
  union { uint4 u4; bf16x8 b; } c; c.u4 = u; return c.b;
}

// ---- fp8 e4m3 encode/decode (HW cvt on gfx950; SW fallback approximate) ----

__device__ inline unsigned char f2fp8(float x){
#ifdef HAS_FP8CVT
  int p = __builtin_amdgcn_cvt_pk_fp8_f32(x, x, 0, false);
  return (unsigned char)(p & 0xFF);
#else
  unsigned u = __float_as_uint(x);
  unsigned s = (u >> 24) & 0x80u;
  unsigned um = u & 0x7FFFFFFFu;
  if (um >= 0x43E00000u) return (unsigned char)(s | 0x7E);      // clamp to 448
  if (um <  0x3C000000u) return (unsigned char)s;               // flush < 2^-7
  unsigned r = um + 0x7FFFFu + ((um >> 20) & 1u);               // RTNE at bit 20
  unsigned e = (r >> 23) & 0xFF, m = (r >> 20) & 7u;
  return (unsigned char)(s | ((e - 120u) << 3) | m);
#endif
}
__device__ inline void fp8x4_to_f32(unsigned v, float& a, float& b, float& c, float& d){
#ifdef HAS_FP8CVT
  f32x2 lo = __builtin_amdgcn_cvt_pk_f32_fp8(v, false);
  f32x2 hi = __builtin_amdgcn_cvt_pk_f32_fp8(v, true);
  a = lo.x; b = lo.y; c = hi.x; d = hi.y;
#else
  auto d1 = [](unsigned char t)->float{
    unsigned s = (t >> 7) & 1u, e = (t >> 3) & 0xFu, m = t & 7u;
    float v = (e == 0) ? ldexpf((float)m, -9) : ldexpf(8.0f + (float)m, (int)e - 10);
    return s ? -v : v;
  };
  a = d1(v & 0xFF); b = d1((v >> 8) & 0xFF); c = d1((v >> 16) & 0xFF); d = d1(v >> 24);
#endif
}

// ---------- CSR build ----------

__global__ void count_kernel(const int* __restrict__ ei, int* __restrict__ cnt, int E){
  int e = blockIdx.x*256 + threadIdx.x;
  if (e < E) atomicAdd(&cnt[ei[E + e]], 1);
}

__global__ void dis_kernel(const int* __restrict__ cnt, float* __restrict__ dis, int N){
  int i = blockIdx.x*256 + threadIdx.x;
  if (i < N) dis[i] = rsqrtf((float)cnt[i] + 1.0f);
}

__global__ void scan_block_kernel(const int* __restrict__ cnt, int* __restrict__ rp,
                                  int* __restrict__ bsum, int N){
  __shared__ int s[2][1024];
  int t = threadIdx.x; int i = blockIdx.x*1024 + t;
  int v = (i < N) ? cnt[i] : 0;
  int cur = 0; s[0][t] = v; __syncthreads();
  for (int off = 1; off < 1024; off <<= 1){
    int nxt = cur ^ 1;
    int val = s[cur][t];
    if (t >= off) val += s[cur][t - off];
    s[nxt][t] = val; cur = nxt; __syncthreads();
  }
  if (i < N) rp[i+1] = s[cur][t];
  if (t == 1023) bsum[blockIdx.x] = s[cur][1023];
}

__global__ void scan_sums_kernel(int* __restrict__ bsum, int nb){
  __shared__ int s[128];
  int t = threadIdx.x;
  if (t < nb) s[t] = bsum[t];
  __syncthreads();
  if (t == 0){ int acc = 0; for (int b = 0; b < nb; b++){ int v = s[b]; s[b] = acc; acc += v; } }
  __syncthreads();
  if (t < nb) bsum[t] = s[t];
}

__global__ void add_off_kernel(int* __restrict__ rp, const int* __restrict__ bsum,
                               int* __restrict__ cnt, int N){
  int i = blockIdx.x*256 + threadIdx.x;
  if (i < N){ rp[i+1] += bsum[i >> 10]; cnt[i] = 0; }
  if (i == 0) rp[0] = 0;
}

__global__ void fill_kernel(const int* __restrict__ ei, const int* __restrict__ rp,
                            int* __restrict__ cnt, int* __restrict__ csrc, int E){
  int e = blockIdx.x*256 + threadIdx.x;
  if (e < E){
    int s = ei[e]; int d = ei[E + e];
    int pos = rp[d] + atomicAdd(&cnt[d], 1);
    csrc[pos] = s;
  }
}

// ---------- pack W (256x256 fp32 [k][n]) into MFMA B-fragment order (bf16) ----------

__global__ void packW_kernel(const float* __restrict__ W, uint4* __restrict__ Wp){
  int idx = blockIdx.x*256 + threadIdx.x;    // 0..8191
  int lane = idx & 63;
  int blk  = idx >> 6;                        // 0..127
  int q    = blk & 7;
  int t16  = blk >> 3;                        // 0..15 (16-col group)
  int n = t16*16 + (lane & 15);
  int k = q*32 + (lane >> 4)*8;
  uint4 v;
  v.x = pk2bf(W[(size_t)(k+0)*256 + n], W[(size_t)(k+1)*256 + n]);
  v.y = pk2bf(W[(size_t)(k+2)*256 + n], W[(size_t)(k+3)*256 + n]);
  v.z = pk2bf(W[(size_t)(k+4)*256 + n], W[(size_t)(k+5)*256 + n]);
  v.w = pk2bf(W[(size_t)(k+6)*256 + n], W[(size_t)(k+7)*256 + n]);
  Wp[idx] = v;
}

// ---------- MFMA GEMM: out[N,256](fp8 e4m3) = A[N,256] @ W[256,256] ----------
// 128x128 tile, 4 waves (2x2), each wave 64x64 via 4x4 tiles of 16x16x32 MFMA.
// B register-resident (128 VGPRs). A double-buffered in LDS. Out stored fp8
// (the consumer is the edge-gather, which is fabric-bytes-bound).

template<bool A_BF16>
__global__ __launch_bounds__(256, 2) void gemm_mfma(const void* __restrict__ Ap,
                                                    const uint4* __restrict__ Wp,
                                                    unsigned char* __restrict__ out, int N){
  __shared__ __align__(16) ushort_t As[2][128][40];
  int tid  = threadIdx.x;
  int lane = tid & 63;
  int wave = tid >> 6;
  int wr = wave >> 1, wc = wave & 1;
  int quad = lane >> 4;
  int l15  = lane & 15;
  int r0 = blockIdx.x * 128;
  int cb = blockIdx.y;

  uint4 bfr[4][8];
  {
    const uint4* wpb = Wp + (size_t)(cb*2 + wc) * 2048;
    #pragma unroll
    for (int ct = 0; ct < 4; ct++)
      #pragma unroll
      for (int q = 0; q < 8; q++)
        bfr[ct][q] = wpb[(ct*8 + q)*64 + lane];
  }

  f32x4 acc[4][4];
  #pragma unroll
  for (int rt = 0; rt < 4; rt++)
    #pragma unroll
    for (int ct = 0; ct < 4; ct++)
      acc[rt][ct] = f32x4{0.f, 0.f, 0.f, 0.f};

  int srow = tid >> 1;
  int shalf = tid & 1;
  int grow = min(r0 + srow, N - 1);

  auto load_stage = [&](int it, uint4& v0, uint4& v1){
    int k0 = it*32 + shalf*16;
    if constexpr (A_BF16){
      const ushort_t* Ab = (const ushort_t*)Ap;
      const uint4* ga = (const uint4*)(Ab + (size_t)grow*256 + k0);
      v0 = ga[0]; v1 = ga[1];
    } else {
      const float* Af = (const float*)Ap;
      const float4* ga = (const float4*)(Af + (size_t)grow*256 + k0);
      float4 f0 = ga[0], f1 = ga[1], f2 = ga[2], f3 = ga[3];
      v0.x = pk2bf(f0.x, f0.y); v0.y = pk2bf(f0.z, f0.w);
      v0.z = pk2bf(f1.x, f1.y); v0.w = pk2bf(f1.z, f1.w);
      v1.x = pk2bf(f2.x, f2.y); v1.y = pk2bf(f2.z, f2.w);
      v1.z = pk2bf(f3.x, f3.y); v1.w = pk2bf(f3.z, f3.w);
    }
  };
  auto write_stage = [&](int b, uint4 v0, uint4 v1){
    *(uint4*)&As[b][srow][shalf*16]     = v0;
    *(uint4*)&As[b][srow][shalf*16 + 8] = v1;
  };

  {
    uint4 v0, v1;
    load_stage(0, v0, v1);
    write_stage(0, v0, v1);
  }
  __syncthreads();

  #pragma unroll
  for (int it = 0; it < 8; it++){
    const int b = it & 1;
    uint4 n0, n1;
    if (it < 7) load_stage(it + 1, n0, n1);
    #pragma unroll
    for (int rt = 0; rt < 4; rt++){
      int arow = wr*64 + rt*16 + l15;
      uint4 av = *(const uint4*)&As[b][arow][quad*8];
      bf16x8 af = as_bf16x8(av);
      #pragma unroll
      for (int ct = 0; ct < 4; ct++)
        acc[rt][ct] = __builtin_amdgcn_mfma_f32_16x16x32_bf16(
            af, as_bf16x8(bfr[ct][it]), acc[rt][ct], 0, 0, 0);
    }
    if (it < 7){
      write_stage(b ^ 1, n0, n1);
      __syncthreads();
    }
  }

  // store C (fp8): row = r0+wr*64+rt*16+quad*4+g, col = cb*128+wc*64+ct*16+l15
  int crow0 = r0 + wr*64 + quad*4;
  int ccol0 = cb*128 + wc*64 + l15;
  #pragma unroll
  for (int rt = 0; rt < 4; rt++){
    #pragma unroll
    for (int g = 0; g < 4; g++){
      int row = crow0 + rt*16 + g;
      if (row < N){
        #pragma unroll
        for (int ct = 0; ct < 4; ct++)
          out[(size_t)row*256 + ccol0 + ct*16] = f2fp8(acc[rt][ct][g]);
      }
    }
  }
}

// ---------- GCN aggregation (fp8 gather -> bf16 out): half-wave (32 lanes) per
// node, 8 fp8 cols per lane as one 8B uint2 load (256B/row, fully coalesced).

__global__ __launch_bounds__(256) void agg_kernel(const unsigned char* __restrict__ xw,
                                                  const float* __restrict__ dis,
                                                  const int* __restrict__ rp,
                                                  const int* __restrict__ csrc,
                                                  const float* __restrict__ bias,
                                                  ushort_t* __restrict__ out, int N){
  int node = blockIdx.x*8 + (threadIdx.x >> 5);
  int lane = threadIdx.x & 31;
  if (node >= N) return;
  const uint2* xw2 = (const uint2*)xw;     // 8 B = 8 fp8; row = 32 uint2
  float di = dis[node];
  float sc = di * di;
  float acc[8];
  {
    uint2 a = xw2[(size_t)node*32 + lane];
    float v0,v1,v2,v3,v4,v5,v6,v7;
    fp8x4_to_f32(a.x, v0, v1, v2, v3);
    fp8x4_to_f32(a.y, v4, v5, v6, v7);
    acc[0]=v0*sc; acc[1]=v1*sc; acc[2]=v2*sc; acc[3]=v3*sc;
    acc[4]=v4*sc; acc[5]=v5*sc; acc[6]=v6*sc; acc[7]=v7*sc;
  }
  int e0 = rp[node], e1 = rp[node+1];
  for (int e = e0; e < e1; e++){
    int s = csrc[e];
    float cc = dis[s] * di;
    uint2 v = xw2[(size_t)s*32 + lane];
    float v0,v1,v2,v3,v4,v5,v6,v7;
    fp8x4_to_f32(v.x, v0, v1, v2, v3);
    fp8x4_to_f32(v.y, v4, v5, v6, v7);
    acc[0] = fmaf(v0, cc, acc[0]);
    acc[1] = fmaf(v1, cc, acc[1]);
    acc[2] = fmaf(v2, cc, acc[2]);
    acc[3] = fmaf(v3, cc, acc[3]);
    acc[4] = fmaf(v4, cc, acc[4]);
    acc[5] = fmaf(v5, cc, acc[5]);
    acc[6] = fmaf(v6, cc, acc[6]);
    acc[7] = fmaf(v7, cc, acc[7]);
  }
  const float4* b4 = (const float4*)bias;   // cols lane*8..lane*8+7
  float4 bA = b4[lane*2], bB = b4[lane*2+1];
  acc[0] = fmaxf(acc[0] + bA.x, 0.f);
  acc[1] = fmaxf(acc[1] + bA.y, 0.f);
  acc[2] = fmaxf(acc[2] + bA.z, 0.f);
  acc[3] = fmaxf(acc[3] + bA.w, 0.f);
  acc[4] = fmaxf(acc[4] + bB.x, 0.f);
  acc[5] = fmaxf(acc[5] + bB.y, 0.f);
  acc[6] = fmaxf(acc[6] + bB.z, 0.f);
  acc[7] = fmaxf(acc[7] + bB.w, 0.f);
  uint4 o;
  o.x = pk2bf(acc[0], acc[1]);
  o.y = pk2bf(acc[2], acc[3]);
  o.z = pk2bf(acc[4], acc[5]);
  o.w = pk2bf(acc[6], acc[7]);
  ((uint4*)out)[(size_t)node*32 + lane] = o;
}

// ---------- mean pool (bf16 input, fp32 accumulate) ----------

__global__ void pool_kernel(const ushort_t* __restrict__ h, const int* __restrict__ ptr,
                            float* __restrict__ hp){
  int t = blockIdx.x; int part = blockIdx.y; int c = threadIdx.x;
  int s0 = ptr[t], s1 = ptr[t+1];
  int len = s1 - s0;
  int chunk = (len + 7) / 8;
  int r0 = s0 + part*chunk;
  int r1 = min(r0 + chunk, s1);
  float acc = 0.f;
  for (int r = r0; r < r1; r++) acc += bf2f(h[(size_t)r*256 + c]);
  if (r1 > r0) atomicAdd(&hp[t*256 + c], acc);
}

// ---------- GX[t,g] = dot(hp[t]/cnt[t], w_ih[g]) + b_ih[g] (div folded in) ----------

__global__ __launch_bounds__(768) void gx_kernel(const float* __restrict__ hp,
                                                 const int* __restrict__ ptr,
                                                 const float* __restrict__ wih,
                                                 const float* __restrict__ bih,
                                                 float* __restrict__ gx){
  __shared__ float xs[256];
  int t = blockIdx.x; int g = threadIdx.x;
  if (g < 256){
    float cf = (float)max(ptr[t+1] - ptr[t], 1);
    xs[g] = hp[t*256 + g] / cf;
  }
  __syncthreads();
  float acc = bih[g];
  const float* wr = wih + (size_t)g*256;
  #pragma unroll 4
  for (int k = 0; k < 256; k++) acc = fmaf(xs[k], wr[k], acc);
  gx[t*768 + g] = acc;
}

// ---------- sequential GRU: single block, 1024 threads (4 threads/gate),
// w_hh register-resident f16 (48 VGPRs), double-buffered h in LDS -> ONE
// barrier per step, next-step gx prefetched, native exp/rcp transcendentals.

__device__ inline float fast_sig(float x){
  return __builtin_amdgcn_rcpf(1.f + __expf(-x));
}
__device__ inline float fast_tanh(float x){
  // 1 - 2/(e^{2x}+1); exact limits at +-inf via rcp(inf)=0
  return 1.f - 2.f*__builtin_amdgcn_rcpf(1.f + __expf(2.f*x));
}

__global__ __launch_bounds__(1024, 4) void gru_kernel(const float* __restrict__ gx,
                                                      const float* __restrict__ whh,
                                                      const float* __restrict__ bhh,
                                                      const float* __restrict__ Wc,
                                                      const float* __restrict__ bc,
                                                      float* __restrict__ out){
  __shared__ _Float16 hh[2][256];
  __shared__ float hfin[256];
  int tid = threadIdx.x;
  int i = tid >> 2;        // gate index 0..255
  int q = tid & 3;         // k-quarter (64 floats = 32 h2 each)

  h2_t wrg[32], wzg[32], wng[32];
  {
    const float2* w2 = (const float2*)whh;
    size_t base = (size_t)q * 32;
    const float2* pr = w2 + (size_t)i*128       + base;
    const float2* pz = w2 + (size_t)(i+256)*128 + base;
    const float2* pn = w2 + (size_t)(i+512)*128 + base;
    #pragma unroll
    for (int k = 0; k < 32; k++){
      float2 a = pr[k];
      float2 b = pz[k];
      float2 c = pn[k];
      wrg[k] = h2_t{(_Float16)a.x, (_Float16)a.y};
      wzg[k] = h2_t{(_Float16)b.x, (_Float16)b.y};
      wng[k] = h2_t{(_Float16)c.x, (_Float16)c.y};
    }
  }
  float bR = bhh[i], bZ = bhh[i+256], bN = bhh[i+512];
  if (tid < 256) hh[0][tid] = (_Float16)0.f;
  float h = 0.f;
  // prefetch t=0 gx
  float gxr = gx[i], gxz = gx[256 + i], gxn = gx[512 + i];
  __syncthreads();

  for (int t = 0; t < 64; t++){
    // prefetch next step's gx; consumed after this step's compute
    float ngr = 0.f, ngz = 0.f, ngn = 0.f;
    if (t < 63){
      const float* g = gx + (size_t)(t+1)*768;
      ngr = g[i]; ngz = g[256 + i]; ngn = g[512 + i];
    }
    const h2_t* hp2 = ((const h2_t*)hh[t & 1]) + q*32;
    float aR0=0.f, aR1=0.f, aZ0=0.f, aZ1=0.f, aN0=0.f, aN1=0.f;
    #pragma unroll
    for (int k = 0; k < 32; k += 2){
      h2_t h0 = hp2[k];
      h2_t h1 = hp2[k+1];
#ifdef HAS_FDOT2
      aR0 = __builtin_amdgcn_fdot2(h0, wrg[k],   aR0, false);
      aZ0 = __builtin_amdgcn_fdot2(h0, wzg[k],   aZ0, false);
      aN0 = __builtin_amdgcn_fdot2(h0, wng[k],   aN0, false);
      aR1 = __builtin_amdgcn_fdot2(h1, wrg[k+1], aR1, false);
      aZ1 = __builtin_amdgcn_fdot2(h1, wzg[k+1], aZ1, false);
      aN1 = __builtin_amdgcn_fdot2(h1, wng[k+1], aN1, false);
#else
      aR0 = fmaf((float)h0.x, (float)wrg[k].x, aR0);
      aR0 = fmaf((float)h0.y, (float)wrg[k].y, aR0);
      aZ0 = fmaf((float)h0.x, (float)wzg[k].x, aZ0);
      aZ0 = fmaf((float)h0.y, (float)wzg[k].y, aZ0);
      aN0 = fmaf((float)h0.x, (float)wng[k].x, aN0);
      aN0 = fmaf((float)h0.y, (float)wng[k].y, aN0);
      aR1 = fmaf((float)h1.x, (float)wrg[k+1].x, aR1);
      aR1 = fmaf((float)h1.y, (float)wrg[k+1].y, aR1);
      aZ1 = fmaf((float)h1.x, (float)wzg[k+1].x, aZ1);
      aZ1 = fmaf((float)h1.y, (float)wzg[k+1].y, aZ1);
      aN1 = fmaf((float)h1.x, (float)wng[k+1].x, aN1);
      aN1 = fmaf((float)h1.y, (float)wng[k+1].y, aN1);
#endif
    }
    float accR = aR0 + aR1, accZ = aZ0 + aZ1, accN = aN0 + aN1;
    accR += __shfl_xor(accR, 1); accR += __shfl_xor(accR, 2);
    accZ += __shfl_xor(accZ, 1); accZ += __shfl_xor(accZ, 2);
    accN += __shfl_xor(accN, 1); accN += __shfl_xor(accN, 2);
    float r = fast_sig(gxr + accR + bR);
    float z = fast_sig(gxz + accZ + bZ);
    float n = fast_tanh(gxn + r*(accN + bN));
    float hnew = (1.f - z)*n + z*h;
    if (q == 0) hh[(t & 1) ^ 1][i] = (_Float16)hnew;
    gxr = ngr; gxz = ngz; gxn = ngn;
    h = hnew;
    __syncthreads();
  }

  if (q == 0) hfin[i] = h;
  __syncthreads();
  if (tid < 64){
    int r = tid >> 2, qq = tid & 3;
    const float4* wrow = (const float4*)(Wc + (size_t)r*256 + (size_t)qq*64);
    const float4* hv = (const float4*)(hfin + (size_t)qq*64);
    float acc = 0.f;
    #pragma unroll
    for (int k = 0; k < 16; k++){
      float4 wv = wrow[k];
      float4 xv = hv[k];
      acc = fmaf(wv.x, xv.x, acc);
      acc = fmaf(wv.y, xv.y, acc);
      acc = fmaf(wv.z, xv.z, acc);
      acc = fmaf(wv.w, xv.w, acc);
    }
    acc += __shfl_xor(acc, 1);
    acc += __shfl_xor(acc, 2);
    if (qq == 0) out[r] = acc + bc[r];
  }
}

extern "C" void kernel_launch(void* const* d_in, const int* in_sizes, int n_in,
                              void* d_out, int out_size, void* d_ws, size_t ws_size,
                              hipStream_t stream){
  const float* x   = (const float*)d_in[0];
  const int*   ei  = (const int*)d_in[1];
  const int*   ptr = (const int*)d_in[2];
  const float* W1  = (const float*)d_in[3];
  const float* b1  = (const float*)d_in[4];
  const float* W2  = (const float*)d_in[5];
  const float* b2  = (const float*)d_in[6];
  const float* wih = (const float*)d_in[7];
  const float* whh = (const float*)d_in[8];
  const float* bih = (const float*)d_in[9];
  const float* bhh = (const float*)d_in[10];
  const float* Wc  = (const float*)d_in[11];
  const float* bc  = (const float*)d_in[12];
  float* outp = (float*)d_out;

  const int N = in_sizes[0] / 256;   // 100000
  const int E = in_sizes[1] / 2;     // 1600000

  char* w = (char*)d_ws;
  size_t off = 0;
  auto alloc = [&](size_t bytes){ void* p = w + off; off = align512(off + bytes); return p; };
  unsigned char* bufA = (unsigned char*)alloc((size_t)N*256);     // xw (fp8 e4m3)
  ushort_t*      bufB = (ushort_t*)alloc((size_t)N*256*2);        // h  (bf16)
  float* dis  = (float*)alloc((size_t)N*4);
  int*   cnt  = (int*)  alloc((size_t)N*4);
  int*   rp   = (int*)  alloc((size_t)(N+1)*4);
  int*   bsum = (int*)  alloc(128*4);
  int*   csrc = (int*)  alloc((size_t)E*4);
  uint4* Wp1  = (uint4*)alloc(8192*16);
  uint4* Wp2  = (uint4*)alloc(8192*16);
  float* hp   = (float*)alloc((size_t)64*256*4);
  float* gxb  = (float*)alloc((size_t)64*768*4);
  (void)ws_size; (void)n_in; (void)out_size;

  hipMemsetAsync(cnt, 0, (size_t)N*4, stream);
  hipMemsetAsync(hp,  0, (size_t)64*256*4, stream);

  // CSR build + degree + weight packing
  count_kernel<<<(E+255)/256, 256, 0, stream>>>(ei, cnt, E);
  dis_kernel<<<(N+255)/256, 256, 0, stream>>>(cnt, dis, N);
  int nb = (N + 1023) / 1024;
  scan_block_kernel<<<nb, 1024, 0, stream>>>(cnt, rp, bsum, N);
  scan_sums_kernel<<<1, 128, 0, stream>>>(bsum, nb);
  add_off_kernel<<<(N+255)/256, 256, 0, stream>>>(rp, bsum, cnt, N);
  fill_kernel<<<(E+255)/256, 256, 0, stream>>>(ei, rp, cnt, csrc, E);
  packW_kernel<<<32, 256, 0, stream>>>(W1, Wp1);
  packW_kernel<<<32, 256, 0, stream>>>(W2, Wp2);

  // GCN layer 1
  gemm_mfma<false><<<dim3((N+127)/128, 2), 256, 0, stream>>>(x, Wp1, bufA, N);
  agg_kernel<<<(N+7)/8, 256, 0, stream>>>(bufA, dis, rp, csrc, b1, bufB, N);
  // GCN layer 2
  gemm_mfma<true><<<dim3((N+127)/128, 2), 256, 0, stream>>>(bufB, Wp2, bufA, N);
  agg_kernel<<<(N+7)/8, 256, 0, stream>>>(bufA, dis, rp, csrc, b2, bufB, N);

  // pool + GRU + classifier
  pool_kernel<<<dim3(64, 8), 256, 0, stream>>>(bufB, ptr, hp);
  gx_kernel<<<64, 768, 0, stream>>>(hp, ptr, wih, bih, gxb);
  gru_kernel<<<1, 1024, 0, stream>>>(gxb, whh, bhh, Wc, bc, outp);
}

// Round 2
// 838.795 us; speedup vs baseline: 1.0002x; 1.0002x over previous
//
#include <hip/hip_runtime.h>
#include <hip/hip_bf16.h>
#include <math.h>

// Problem constants (fixed by reference): N=100000 nodes, E=1.6M edges, H=256, T=64.

static inline size_t align512(size_t x){ return (x + 511) & ~size_t(511); }

typedef _Float16 h2_t __attribute__((ext_vector_type(2)));
typedef unsigned short ushort_t;
typedef short bf16x8 __attribute__((ext_vector_type(8)));   // 8 bf16 = 4 VGPRs (MFMA A/B frag)
typedef float f32x4 __attribute__((ext_vector_type(4)));    // MFMA C/D frag
typedef float f32x2 __attribute__((ext_vector_type(2)));

#if defined(__has_builtin)
#if __has_builtin(__builtin_amdgcn_fdot2)
#define HAS_FDOT2 1
#endif
#if __has_builtin(__builtin_amdgcn_cvt_pk_f32_fp8) && __has_builtin(__builtin_amdgcn_cvt_pk_fp8_f32)
#define HAS_FP8CVT 1
#endif
#endif

__device__ inline ushort_t f2bf(float f){
  unsigned u = __float_as_uint(f);
  unsigned r = u + 0x7FFFu + ((u >> 16) & 1u);   // RTNE
  return (ushort_t)(r >> 16);
}
__device__ inline float bf2f(ushort_t h){ return __uint_as_float(((unsigned)h) << 16); }
__device__ inline unsigned pk2bf(float lo, float hi){
  return ((unsigned)f2bf(hi) << 16) | (unsigned)f2bf(lo);
}
__device__ inline bf16x8 as_bf16x8(uint4 u){
  union { uint4 u4; bf16x8 b; } c; c.u4 = u; return c.b;
}

// ---- fp8 e4m3 encode/decode (HW cvt on gfx950; SW fallback approximate) ----

__device__ inline unsigned char f2fp8(float x){
#ifdef HAS_FP8CVT
  int p = __builtin_amdgcn_cvt_pk_fp8_f32(x, x, 0, false);
  return (unsigned char)(p & 0xFF);
#else
  unsigned u = __float_as_uint(x);
  unsigned s = (u >> 24) & 0x80u;
  unsigned um = u & 0x7FFFFFFFu;
  if (um >= 0x43E00000u) return (unsigned char)(s | 0x7E);      // clamp to 448
  if (um <  0x3C000000u) return (unsigned char)s;               // flush < 2^-7
  unsigned r = um + 0x7FFFFu + ((um >> 20) & 1u);               // RTNE at bit 20
  unsigned e = (r >> 23) & 0xFF, m = (r >> 20) & 7u;
  return (unsigned char)(s | ((e - 120u) << 3) | m);
#endif
}
__device__ inline void fp8x4_to_f32(unsigned v, float& a, float& b, float& c, float& d){
#ifdef HAS_FP8CVT
  f32x2 lo = __builtin_amdgcn_cvt_pk_f32_fp8(v, false);
  f32x2 hi = __builtin_amdgcn_cvt_pk_f32_fp8(v, true);
  a = lo.x; b = lo.y; c = hi.x; d = hi.y;
#else
  auto d1 = [](unsigned char t)->float{
    unsigned s = (t >> 7) & 1u, e = (t >> 3) & 0xFu, m = t & 7u;
    float v = (e == 0) ? ldexpf((float)m, -9) : ldexpf(8.0f + (float)m, (int)e - 10);
    return s ? -v : v;
  };
  a = d1(v & 0xFF); b = d1((v >> 8) & 0xFF); c = d1((v >> 16) & 0xFF); d = d1(v >> 24);
#endif
}

// ---------- CSR build ----------

__global__ void count_kernel(const int* __restrict__ ei, int* __restrict__ cnt, int E){
  int e = blockIdx.x*256 + threadIdx.x;
  if (e < E) atomicAdd(&cnt[ei[E + e]], 1);
}

__global__ void dis_kernel(const int* __restrict__ cnt, float* __restrict__ dis, int N){
  int i = blockIdx.x*256 + threadIdx.x;
  if (i < N) dis[i] = rsqrtf((float)cnt[i] + 1.0f);
}

__global__ void scan_block_kernel(const int* __restrict__ cnt, int* __restrict__ rp,
                                  int* __restrict__ bsum, int N){
  __shared__ int s[2][1024];
  int t = threadIdx.x; int i = blockIdx.x*1024 + t;
  int v = (i < N) ? cnt[i] : 0;
  int cur = 0; s[0][t] = v; __syncthreads();
  for (int off = 1; off < 1024; off <<= 1){
    int nxt = cur ^ 1;
    int val = s[cur][t];
    if (t >= off) val += s[cur][t - off];
    s[nxt][t] = val; cur = nxt; __syncthreads();
  }
  if (i < N) rp[i+1] = s[cur][t];
  if (t == 1023) bsum[blockIdx.x] = s[cur][1023];
}

__global__ void scan_sums_kernel(int* __restrict__ bsum, int nb){
  __shared__ int s[128];
  int t = threadIdx.x;
  if (t < nb) s[t] = bsum[t];
  __syncthreads();
  if (t == 0){ int acc = 0; for (int b = 0; b < nb; b++){ int v = s[b]; s[b] = acc; acc += v; } }
  __syncthreads();
  if (t < nb) bsum[t] = s[t];
}

__global__ void add_off_kernel(int* __restrict__ rp, const int* __restrict__ bsum,
                               int* __restrict__ cnt, int N){
  int i = blockIdx.x*256 + threadIdx.x;
  if (i < N){ rp[i+1] += bsum[i >> 10]; cnt[i] = 0; }
  if (i == 0) rp[0] = 0;
}

__global__ void fill_kernel(const int* __restrict__ ei, const int* __restrict__ rp,
                            int* __restrict__ cnt, int* __restrict__ csrc, int E){
  int e = blockIdx.x*256 + threadIdx.x;
  if (e < E){
    int s = ei[e]; int d = ei[E + e];
    int pos = rp[d] + atomicAdd(&cnt[d], 1);
    csrc[pos] = s;
  }
}

// ---------- pack W (256x256 fp32 [k][n]) into MFMA B-fragment order (bf16) ----------

__global__ void packW_kernel(const float* __restrict__ W, uint4* __restrict__ Wp){
  int idx = blockIdx.x*256 + threadIdx.x;    // 0..8191
  int lane = idx & 63;
  int blk  = idx >> 6;                        // 0..127
  int q    = blk & 7;
  int t16  = blk >> 3;                        // 0..15 (16-col group)
  int n = t16*16 + (lane & 15);
  int k = q*32 + (lane >> 4)*8;
  uint4 v;
  v.x = pk2bf(W[(size_t)(k+0)*256 + n], W[(size_t)(k+1)*256 + n]);
  v.y = pk2bf(W[(size_t)(k+2)*256 + n], W[(size_t)(k+3)*256 + n]);
  v.z = pk2bf(W[(size_t)(k+4)*256 + n], W[(size_t)(k+5)*256 + n]);
  v.w = pk2bf(W[(size_t)(k+6)*256 + n], W[(size_t)(k+7)*256 + n]);
  Wp[idx] = v;
}

// ---------- MFMA GEMM: out[N,256](fp8 e4m3) = A[N,256] @ W[256,256] ----------
// 128x128 tile, 4 waves (2x2), each wave 64x64 via 4x4 tiles of 16x16x32 MFMA.
// B register-resident (128 VGPRs). A double-buffered in LDS. Out stored fp8
// (the consumer is the edge-gather, which is fabric-bytes-bound).

template<bool A_BF16>
__global__ __launch_bounds__(256, 2) void gemm_mfma(const void* __restrict__ Ap,
                                                    const uint4* __restrict__ Wp,
                                                    unsigned char* __restrict__ out, int N){
  __shared__ __align__(16) ushort_t As[2][128][40];
  int tid  = threadIdx.x;
  int lane = tid & 63;
  int wave = tid >> 6;
  int wr = wave >> 1, wc = wave & 1;
  int quad = lane >> 4;
  int l15  = lane & 15;
  int r0 = blockIdx.x * 128;
  int cb = blockIdx.y;

  uint4 bfr[4][8];
  {
    const uint4* wpb = Wp + (size_t)(cb*2 + wc) * 2048;
    #pragma unroll
    for (int ct = 0; ct < 4; ct++)
      #pragma unroll
      for (int q = 0; q < 8; q++)
        bfr[ct][q] = wpb[(ct*8 + q)*64 + lane];
  }

  f32x4 acc[4][4];
  #pragma unroll
  for (int rt = 0; rt < 4; rt++)
    #pragma unroll
    for (int ct = 0; ct < 4; ct++)
      acc[rt][ct] = f32x4{0.f, 0.f, 0.f, 0.f};

  int srow = tid >> 1;
  int shalf = tid & 1;
  int grow = min(r0 + srow, N - 1);

  auto load_stage = [&](int it, uint4& v0, uint4& v1){
    int k0 = it*32 + shalf*16;
    if constexpr (A_BF16){
      const ushort_t* Ab = (const ushort_t*)Ap;
      const uint4* ga = (const uint4*)(Ab + (size_t)grow*256 + k0);
      v0 = ga[0]; v1 = ga[1];
    } else {
      const float* Af = (const float*)Ap;
      const float4* ga = (const float4*)(Af + (size_t)grow*256 + k0);
      float4 f0 = ga[0], f1 = ga[1], f2 = ga[2], f3 = ga[3];
      v0.x = pk2bf(f0.x, f0.y); v0.y = pk2bf(f0.z, f0.w);
      v0.z = pk2bf(f1.x, f1.y); v0.w = pk2bf(f1.z, f1.w);
      v1.x = pk2bf(f2.x, f2.y); v1.y = pk2bf(f2.z, f2.w);
      v1.z = pk2bf(f3.x, f3.y); v1.w = pk2bf(f3.z, f3.w);
    }
  };
  auto write_stage = [&](int b, uint4 v0, uint4 v1){
    *(uint4*)&As[b][srow][shalf*16]     = v0;
    *(uint4*)&As[b][srow][shalf*16 + 8] = v1;
  };

  {
    uint4 v0, v1;
    load_stage(0, v0, v1);
    write_stage(0, v0, v1);
  }
  __syncthreads();

  #pragma unroll
  for (int it = 0; it < 8; it++){
    const int b = it & 1;
    uint4 n0, n1;
    if (it < 7) load_stage(it + 1, n0, n1);
    #pragma unroll
    for (int rt = 0; rt < 4; rt++){
      int arow = wr*64 + rt*16 + l15;
      uint4 av = *(const uint4*)&As[b][arow][quad*8];
      bf16x8 af = as_bf16x8(av);
      #pragma unroll
      for (int ct = 0; ct < 4; ct++)
        acc[rt][ct] = __builtin_amdgcn_mfma_f32_16x16x32_bf16(
            af, as_bf16x8(bfr[ct][it]), acc[rt][ct], 0, 0, 0);
    }
    if (it < 7){
      write_stage(b ^ 1, n0, n1);
      __syncthreads();
    }
  }

  // store C (fp8): row = r0+wr*64+rt*16+quad*4+g, col = cb*128+wc*64+ct*16+l15
  int crow0 = r0 + wr*64 + quad*4;
  int ccol0 = cb*128 + wc*64 + l15;
  #pragma unroll
  for (int rt = 0; rt < 4; rt++){
    #pragma unroll
    for (int g = 0; g < 4; g++){
      int row = crow0 + rt*16 + g;
      if (row < N){
        #pragma unroll
        for (int ct = 0; ct < 4; ct++)
          out[(size_t)row*256 + ccol0 + ct*16] = f2fp8(acc[rt][ct][g]);
      }
    }
  }
}

// ---------- GCN aggregation (fp8 gather -> bf16 out): half-wave (32 lanes) per
// node, 8 fp8 cols per lane as one 8B uint2 load (256B/row, fully coalesced).

__global__ __launch_bounds__(256) void agg_kernel(const unsigned char* __restrict__ xw,
                                                  const float* __restrict__ dis,
                                                  const int* __restrict__ rp,
                                                  const int* __restrict__ csrc,
                                                  const float* __restrict__ bias,
                                                  ushort_t* __restrict__ out, int N){
  int node = blockIdx.x*8 + (threadIdx.x >> 5);
  int lane = threadIdx.x & 31;
  if (node >= N) return;
  const uint2* xw2 = (const uint2*)xw;     // 8 B = 8 fp8; row = 32 uint2
  float di = dis[node];
  float sc = di * di;
  float acc[8];
  {
    uint2 a = xw2[(size_t)node*32 + lane];
    float v0,v1,v2,v3,v4,v5,v6,v7;
    fp8x4_to_f32(a.x, v0, v1, v2, v3);
    fp8x4_to_f32(a.y, v4, v5, v6, v7);
    acc[0]=v0*sc; acc[1]=v1*sc; acc[2]=v2*sc; acc[3]=v3*sc;
    acc[4]=v4*sc; acc[5]=v5*sc; acc[6]=v6*sc; acc[7]=v7*sc;
  }
  int e0 = rp[node], e1 = rp[node+1];
  for (int e = e0; e < e1; e++){
    int s = csrc[e];
    float cc = dis[s] * di;
    uint2 v = xw2[(size_t)s*32 + lane];
    float v0,v1,v2,v3,v4,v5,v6,v7;
    fp8x4_to_f32(v.x, v0, v1, v2, v3);
    fp8x4_to_f32(v.y, v4, v5, v6, v7);
    acc[0] = fmaf(v0, cc, acc[0]);
    acc[1] = fmaf(v1, cc, acc[1]);
    acc[2] = fmaf(v2, cc, acc[2]);
    acc[3] = fmaf(v3, cc, acc[3]);
    acc[4] = fmaf(v4, cc, acc[4]);
    acc[5] = fmaf(v5, cc, acc[5]);
    acc[6] = fmaf(v6, cc, acc[6]);
    acc[7] = fmaf(v7, cc, acc[7]);
  }
  const float4* b4 = (const float4*)bias;   // cols lane*8..lane*8+7
  float4 bA = b4[lane*2], bB = b4[lane*2+1];
  acc[0] = fmaxf(acc[0] + bA.x, 0.f);
  acc[1] = fmaxf(acc[1] + bA.y, 0.f);
  acc[2] = fmaxf(acc[2] + bA.z, 0.f);
  acc[3] = fmaxf(acc[3] + bA.w, 0.f);
  acc[4] = fmaxf(acc[4] + bB.x, 0.f);
  acc[5] = fmaxf(acc[5] + bB.y, 0.f);
  acc[6] = fmaxf(acc[6] + bB.z, 0.f);
  acc[7] = fmaxf(acc[7] + bB.w, 0.f);
  uint4 o;
  o.x = pk2bf(acc[0], acc[1]);
  o.y = pk2bf(acc[2], acc[3]);
  o.z = pk2bf(acc[4], acc[5]);
  o.w = pk2bf(acc[6], acc[7]);
  ((uint4*)out)[(size_t)node*32 + lane] = o;
}

// ---------- mean pool (bf16 input, fp32 accumulate) ----------

__global__ void pool_kernel(const ushort_t* __restrict__ h, const int* __restrict__ ptr,
                            float* __restrict__ hp){
  int t = blockIdx.x; int part = blockIdx.y; int c = threadIdx.x;
  int s0 = ptr[t], s1 = ptr[t+1];
  int len = s1 - s0;
  int chunk = (len + 7) / 8;
  int r0 = s0 + part*chunk;
  int r1 = min(r0 + chunk, s1);
  float acc = 0.f;
  for (int r = r0; r < r1; r++) acc += bf2f(h[(size_t)r*256 + c]);
  if (r1 > r0) atomicAdd(&hp[t*256 + c], acc);
}

// ---------- GX[t,g] = dot(hp[t]/cnt[t], w_ih[g]) + b_ih[g] (div folded in) ----------

__global__ __launch_bounds__(768) void gx_kernel(const float* __restrict__ hp,
                                                 const int* __restrict__ ptr,
                                                 const float* __restrict__ wih,
                                                 const float* __restrict__ bih,
                                                 float* __restrict__ gx){
  __shared__ float xs[256];
  int t = blockIdx.x; int g = threadIdx.x;
  if (g < 256){
    float cf = (float)max(ptr[t+1] - ptr[t], 1);
    xs[g] = hp[t*256 + g] / cf;
  }
  __syncthreads();
  float acc = bih[g];
  const float* wr = wih + (size_t)g*256;
  #pragma unroll 4
  for (int k = 0; k < 256; k++) acc = fmaf(xs[k], wr[k], acc);
  gx[t*768 + g] = acc;
}

// ---------- sequential GRU: single block, 1024 threads (4 threads/gate),
// w_hh register-resident f16 (96 VGPRs), double-buffered h in LDS -> ONE
// barrier per step, next-step gx prefetched, native exp/rcp transcendentals.
// __launch_bounds__(1024, 1): 1 block/CU -> 4 waves/SIMD -> 128-VGPR cap.
// (Second arg is min BLOCKS/CU, CUDA semantics: (1024,4) capped VGPRs at 64
// and spilled all 96 weight regs -> 320KB scratch writes, 150us. Measured.)

__device__ inline float fast_sig(float x){
  return __builtin_amdgcn_rcpf(1.f + __expf(-x));
}
__device__ inline float fast_tanh(float x){
  // 1 - 2/(e^{2x}+1); exact limits at +-inf via rcp(inf)=0
  return 1.f - 2.f*__builtin_amdgcn_rcpf(1.f + __expf(2.f*x));
}

__global__ __launch_bounds__(1024, 1) void gru_kernel(const float* __restrict__ gx,
                                                      const float* __restrict__ whh,
                                                      const float* __restrict__ bhh,
                                                      const float* __restrict__ Wc,
                                                      const float* __restrict__ bc,
                                                      float* __restrict__ out){
  __shared__ _Float16 hh[2][256];
  __shared__ float hfin[256];
  int tid = threadIdx.x;
  int i = tid >> 2;        // gate index 0..255
  int q = tid & 3;         // k-quarter (64 floats = 32 h2 each)

  h2_t wrg[32], wzg[32], wng[32];
  {
    const float2* w2 = (const float2*)whh;
    size_t base = (size_t)q * 32;
    const float2* pr = w2 + (size_t)i*128       + base;
    const float2* pz = w2 + (size_t)(i+256)*128 + base;
    const float2* pn = w2 + (size_t)(i+512)*128 + base;
    #pragma unroll
    for (int k = 0; k < 32; k++){
      float2 a = pr[k];
      float2 b = pz[k];
      float2 c = pn[k];
      wrg[k] = h2_t{(_Float16)a.x, (_Float16)a.y};
      wzg[k] = h2_t{(_Float16)b.x, (_Float16)b.y};
      wng[k] = h2_t{(_Float16)c.x, (_Float16)c.y};
    }
  }
  float bR = bhh[i], bZ = bhh[i+256], bN = bhh[i+512];
  if (tid < 256) hh[0][tid] = (_Float16)0.f;
  float h = 0.f;
  // prefetch t=0 gx
  float gxr = gx[i], gxz = gx[256 + i], gxn = gx[512 + i];
  __syncthreads();

  for (int t = 0; t < 64; t++){
    // prefetch next step's gx; consumed after this step's compute
    float ngr = 0.f, ngz = 0.f, ngn = 0.f;
    if (t < 63){
      const float* g = gx + (size_t)(t+1)*768;
      ngr = g[i]; ngz = g[256 + i]; ngn = g[512 + i];
    }
    const h2_t* hp2 = ((const h2_t*)hh[t & 1]) + q*32;
    float aR0=0.f, aR1=0.f, aZ0=0.f, aZ1=0.f, aN0=0.f, aN1=0.f;
    #pragma unroll
    for (int k = 0; k < 32; k += 2){
      h2_t h0 = hp2[k];
      h2_t h1 = hp2[k+1];
#ifdef HAS_FDOT2
      aR0 = __builtin_amdgcn_fdot2(h0, wrg[k],   aR0, false);
      aZ0 = __builtin_amdgcn_fdot2(h0, wzg[k],   aZ0, false);
      aN0 = __builtin_amdgcn_fdot2(h0, wng[k],   aN0, false);
      aR1 = __builtin_amdgcn_fdot2(h1, wrg[k+1], aR1, false);
      aZ1 = __builtin_amdgcn_fdot2(h1, wzg[k+1], aZ1, false);
      aN1 = __builtin_amdgcn_fdot2(h1, wng[k+1], aN1, false);
#else
      aR0 = fmaf((float)h0.x, (float)wrg[k].x, aR0);
      aR0 = fmaf((float)h0.y, (float)wrg[k].y, aR0);
      aZ0 = fmaf((float)h0.x, (float)wzg[k].x, aZ0);
      aZ0 = fmaf((float)h0.y, (float)wzg[k].y, aZ0);
      aN0 = fmaf((float)h0.x, (float)wng[k].x, aN0);
      aN0 = fmaf((float)h0.y, (float)wng[k].y, aN0);
      aR1 = fmaf((float)h1.x, (float)wrg[k+1].x, aR1);
      aR1 = fmaf((float)h1.y, (float)wrg[k+1].y, aR1);
      aZ1 = fmaf((float)h1.x, (float)wzg[k+1].x, aZ1);
      aZ1 = fmaf((float)h1.y, (float)wzg[k+1].y, aZ1);
      aN1 = fmaf((float)h1.x, (float)wng[k+1].x, aN1);
      aN1 = fmaf((float)h1.y, (float)wng[k+1].y, aN1);
#endif
    }
    float accR = aR0 + aR1, accZ = aZ0 + aZ1, accN = aN0 + aN1;
    accR += __shfl_xor(accR, 1); accR += __shfl_xor(accR, 2);
    accZ += __shfl_xor(accZ, 1); accZ += __shfl_xor(accZ, 2);
    accN += __shfl_xor(accN, 1); accN += __shfl_xor(accN, 2);
    float r = fast_sig(gxr + accR + bR);
    float z = fast_sig(gxz + accZ + bZ);
    float n = fast_tanh(gxn + r*(accN + bN));
    float hnew = (1.f - z)*n + z*h;
    if (q == 0) hh[(t & 1) ^ 1][i] = (_Float16)hnew;
    gxr = ngr; gxz = ngz; gxn = ngn;
    h = hnew;
    __syncthreads();
  }

  if (q == 0) hfin[i] = h;
  __syncthreads();
  if (tid < 64){
    int r = tid >> 2, qq = tid & 3;
    const float4* wrow = (const float4*)(Wc + (size_t)r*256 + (size_t)qq*64);
    const float4* hv = (const float4*)(hfin + (size_t)qq*64);
    float acc = 0.f;
    #pragma unroll
    for (int k = 0; k < 16; k++){
      float4 wv = wrow[k];
      float4 xv = hv[k];
      acc = fmaf(wv.x, xv.x, acc);
      acc = fmaf(wv.y, xv.y, acc);
      acc = fmaf(wv.z, xv.z, acc);
      acc = fmaf(wv.w, xv.w, acc);
    }
    acc += __shfl_xor(acc, 1);
    acc += __shfl_xor(acc, 2);
    if (qq == 0) out[r] = acc + bc[r];
  }
}

extern "C" void kernel_launch(void* const* d_in, const int* in_sizes, int n_in,
                              void* d_out, int out_size, void* d_ws, size_t ws_size,
                              hipStream_t stream){
  const float* x   = (const float*)d_in[0];
  const int*   ei  = (const int*)d_in[1];
  const int*   ptr = (const int*)d_in[2];
  const float* W1  = (const float*)d_in[3];
  const float* b1  = (const float*)d_in[4];
  const float* W2  = (const float*)d_in[5];
  const float* b2  = (const float*)d_in[6];
  const float* wih = (const float*)d_in[7];
  const float* whh = (const float*)d_in[8];
  const float* bih = (const float*)d_in[9];
  const float* bhh = (const float*)d_in[10];
  const float* Wc  = (const float*)d_in[11];
  const float* bc  = (const float*)d_in[12];
  float* outp = (float*)d_out;

  const int N = in_sizes[0] / 256;   // 100000
  const int E = in_sizes[1] / 2;     // 1600000

  char* w = (char*)d_ws;
  size_t off = 0;
  auto alloc = [&](size_t bytes){ void* p = w + off; off = align512(off + bytes); return p; };
  unsigned char* bufA = (unsigned char*)alloc((size_t)N*256);     // xw (fp8 e4m3)
  ushort_t*      bufB = (ushort_t*)alloc((size_t)N*256*2);        // h  (bf16)
  float* dis  = (float*)alloc((size_t)N*4);
  int*   cnt  = (int*)  alloc((size_t)N*4);
  int*   rp   = (int*)  alloc((size_t)(N+1)*4);
  int*   bsum = (int*)  alloc(128*4);
  int*   csrc = (int*)  alloc((size_t)E*4);
  uint4* Wp1  = (uint4*)alloc(8192*16);
  uint4* Wp2  = (uint4*)alloc(8192*16);
  float* hp   = (float*)alloc((size_t)64*256*4);
  float* gxb  = (float*)alloc((size_t)64*768*4);
  (void)ws_size; (void)n_in; (void)out_size;

  hipMemsetAsync(cnt, 0, (size_t)N*4, stream);
  hipMemsetAsync(hp,  0, (size_t)64*256*4, stream);

  // CSR build + degree + weight packing
  count_kernel<<<(E+255)/256, 256, 0, stream>>>(ei, cnt, E);
  dis_kernel<<<(N+255)/256, 256, 0, stream>>>(cnt, dis, N);
  int nb = (N + 1023) / 1024;
  scan_block_kernel<<<nb, 1024, 0, stream>>>(cnt, rp, bsum, N);
  scan_sums_kernel<<<1, 128, 0, stream>>>(bsum, nb);
  add_off_kernel<<<(N+255)/256, 256, 0, stream>>>(rp, bsum, cnt, N);
  fill_kernel<<<(E+255)/256, 256, 0, stream>>>(ei, rp, cnt, csrc, E);
  packW_kernel<<<32, 256, 0, stream>>>(W1, Wp1);
  packW_kernel<<<32, 256, 0, stream>>>(W2, Wp2);

  // GCN layer 1
  gemm_mfma<false><<<dim3((N+127)/128, 2), 256, 0, stream>>>(x, Wp1, bufA, N);
  agg_kernel<<<(N+7)/8, 256, 0, stream>>>(bufA, dis, rp, csrc, b1, bufB, N);
  // GCN layer 2
  gemm_mfma<true><<<dim3((N+127)/128, 2), 256, 0, stream>>>(bufB, Wp2, bufA, N);
  agg_kernel<<<(N+7)/8, 256, 0, stream>>>(bufA, dis, rp, csrc, b2, bufB, N);

  // pool + GRU + classifier
  pool_kernel<<<dim3(64, 8), 256, 0, stream>>>(bufB, ptr, hp);
  gx_kernel<<<64, 768, 0, stream>>>(hp, ptr, wih, bih, gxb);
  gru_kernel<<<1, 1024, 0, stream>>>(gxb, whh, bhh, Wc, bc, outp);
}

// Round 3
// 836.292 us; speedup vs baseline: 1.0032x; 1.0030x over previous
//
#include <hip/hip_runtime.h>
#include <hip/hip_bf16.h>
#include <math.h>

// Problem constants (fixed by reference): N=100000 nodes, E=1.6M edges, H=256, T=64.

static inline size_t align512(size_t x){ return (x + 511) & ~size_t(511); }

typedef _Float16 h2_t __attribute__((ext_vector_type(2)));
typedef unsigned short ushort_t;
typedef short bf16x8 __attribute__((ext_vector_type(8)));   // 8 bf16 = 4 VGPRs (MFMA A/B frag)
typedef float f32x4 __attribute__((ext_vector_type(4)));    // MFMA C/D frag
typedef float f32x2 __attribute__((ext_vector_type(2)));

#if defined(__has_builtin)
#if __has_builtin(__builtin_amdgcn_fdot2)
#define HAS_FDOT2 1
#endif
#if __has_builtin(__builtin_amdgcn_cvt_pk_f32_fp8) && __has_builtin(__builtin_amdgcn_cvt_pk_fp8_f32)
#define HAS_FP8CVT 1
#endif
#endif

__device__ inline ushort_t f2bf(float f){
  unsigned u = __float_as_uint(f);
  unsigned r = u + 0x7FFFu + ((u >> 16) & 1u);   // RTNE
  return (ushort_t)(r >> 16);
}
__device__ inline float bf2f(ushort_t h){ return __uint_as_float(((unsigned)h) << 16); }
__device__ inline unsigned pk2bf(float lo, float hi){
  return ((unsigned)f2bf(hi) << 16) | (unsigned)f2bf(lo);
}
__device__ inline bf16x8 as_bf16x8(uint4 u){
  union { uint4 u4; bf16x8 b; } c; c.u4 = u; return c.b;
}

// ---- fp8 e4m3 encode/decode (HW cvt on gfx950; SW fallback approximate) ----

__device__ inline unsigned char f2fp8(float x){
#ifdef HAS_FP8CVT
  int p = __builtin_amdgcn_cvt_pk_fp8_f32(x, x, 0, false);
  return (unsigned char)(p & 0xFF);
#else
  unsigned u = __float_as_uint(x);
  unsigned s = (u >> 24) & 0x80u;
  unsigned um = u & 0x7FFFFFFFu;
  if (um >= 0x43E00000u) return (unsigned char)(s | 0x7E);      // clamp to 448
  if (um <  0x3C000000u) return (unsigned char)s;               // flush < 2^-7
  unsigned r = um + 0x7FFFFu + ((um >> 20) & 1u);               // RTNE at bit 20
  unsigned e = (r >> 23) & 0xFF, m = (r >> 20) & 7u;
  return (unsigned char)(s | ((e - 120u) << 3) | m);
#endif
}
__device__ inline void fp8x4_to_f32(unsigned v, float& a, float& b, float& c, float& d){
#ifdef HAS_FP8CVT
  f32x2 lo = __builtin_amdgcn_cvt_pk_f32_fp8(v, false);
  f32x2 hi = __builtin_amdgcn_cvt_pk_f32_fp8(v, true);
  a = lo.x; b = lo.y; c = hi.x; d = hi.y;
#else
  auto d1 = [](unsigned char t)->float{
    unsigned s = (t >> 7) & 1u, e = (t >> 3) & 0xFu, m = t & 7u;
    float v = (e == 0) ? ldexpf((float)m, -9) : ldexpf(8.0f + (float)m, (int)e - 10);
    return s ? -v : v;
  };
  a = d1(v & 0xFF); b = d1((v >> 8) & 0xFF); c = d1((v >> 16) & 0xFF); d = d1(v >> 24);
#endif
}

// ---------- CSR build ----------

__global__ void count_kernel(const int* __restrict__ ei, int* __restrict__ cnt, int E){
  int e = blockIdx.x*256 + threadIdx.x;
  if (e < E) atomicAdd(&cnt[ei[E + e]], 1);
}

__global__ void dis_kernel(const int* __restrict__ cnt, float* __restrict__ dis, int N){
  int i = blockIdx.x*256 + threadIdx.x;
  if (i < N) dis[i] = rsqrtf((float)cnt[i] + 1.0f);
}

__global__ void scan_block_kernel(const int* __restrict__ cnt, int* __restrict__ rp,
                                  int* __restrict__ bsum, int N){
  __shared__ int s[2][1024];
  int t = threadIdx.x; int i = blockIdx.x*1024 + t;
  int v = (i < N) ? cnt[i] : 0;
  int cur = 0; s[0][t] = v; __syncthreads();
  for (int off = 1; off < 1024; off <<= 1){
    int nxt = cur ^ 1;
    int val = s[cur][t];
    if (t >= off) val += s[cur][t - off];
    s[nxt][t] = val; cur = nxt; __syncthreads();
  }
  if (i < N) rp[i+1] = s[cur][t];
  if (t == 1023) bsum[blockIdx.x] = s[cur][1023];
}

__global__ void scan_sums_kernel(int* __restrict__ bsum, int nb){
  __shared__ int s[128];
  int t = threadIdx.x;
  if (t < nb) s[t] = bsum[t];
  __syncthreads();
  if (t == 0){ int acc = 0; for (int b = 0; b < nb; b++){ int v = s[b]; s[b] = acc; acc += v; } }
  __syncthreads();
  if (t < nb) bsum[t] = s[t];
}

__global__ void add_off_kernel(int* __restrict__ rp, const int* __restrict__ bsum,
                               int* __restrict__ cnt, int N){
  int i = blockIdx.x*256 + threadIdx.x;
  if (i < N){ rp[i+1] += bsum[i >> 10]; cnt[i] = 0; }
  if (i == 0) rp[0] = 0;
}

__global__ void fill_kernel(const int* __restrict__ ei, const int* __restrict__ rp,
                            int* __restrict__ cnt, int* __restrict__ csrc, int E){
  int e = blockIdx.x*256 + threadIdx.x;
  if (e < E){
    int s = ei[e]; int d = ei[E + e];
    int pos = rp[d] + atomicAdd(&cnt[d], 1);
    csrc[pos] = s;
  }
}

// ---------- pack W (256x256 fp32 [k][n]) into MFMA B-fragment order (bf16) ----------

__global__ void packW_kernel(const float* __restrict__ W, uint4* __restrict__ Wp){
  int idx = blockIdx.x*256 + threadIdx.x;    // 0..8191
  int lane = idx & 63;
  int blk  = idx >> 6;                        // 0..127
  int q    = blk & 7;
  int t16  = blk >> 3;                        // 0..15 (16-col group)
  int n = t16*16 + (lane & 15);
  int k = q*32 + (lane >> 4)*8;
  uint4 v;
  v.x = pk2bf(W[(size_t)(k+0)*256 + n], W[(size_t)(k+1)*256 + n]);
  v.y = pk2bf(W[(size_t)(k+2)*256 + n], W[(size_t)(k+3)*256 + n]);
  v.z = pk2bf(W[(size_t)(k+4)*256 + n], W[(size_t)(k+5)*256 + n]);
  v.w = pk2bf(W[(size_t)(k+6)*256 + n], W[(size_t)(k+7)*256 + n]);
  Wp[idx] = v;
}

// ---------- MFMA GEMM: out[N,256](fp8 e4m3) = A[N,256] @ W[256,256] ----------
// 128x128 tile, 4 waves (2x2), each wave 64x64 via 4x4 tiles of 16x16x32 MFMA.
// B register-resident (128 VGPRs). A double-buffered in LDS. Out stored fp8
// (the consumer is the edge-gather, which is fabric-bytes-bound).

template<bool A_BF16>
__global__ __launch_bounds__(256, 2) void gemm_mfma(const void* __restrict__ Ap,
                                                    const uint4* __restrict__ Wp,
                                                    unsigned char* __restrict__ out, int N){
  __shared__ __align__(16) ushort_t As[2][128][40];
  int tid  = threadIdx.x;
  int lane = tid & 63;
  int wave = tid >> 6;
  int wr = wave >> 1, wc = wave & 1;
  int quad = lane >> 4;
  int l15  = lane & 15;
  int r0 = blockIdx.x * 128;
  int cb = blockIdx.y;

  uint4 bfr[4][8];
  {
    const uint4* wpb = Wp + (size_t)(cb*2 + wc) * 2048;
    #pragma unroll
    for (int ct = 0; ct < 4; ct++)
      #pragma unroll
      for (int q = 0; q < 8; q++)
        bfr[ct][q] = wpb[(ct*8 + q)*64 + lane];
  }

  f32x4 acc[4][4];
  #pragma unroll
  for (int rt = 0; rt < 4; rt++)
    #pragma unroll
    for (int ct = 0; ct < 4; ct++)
      acc[rt][ct] = f32x4{0.f, 0.f, 0.f, 0.f};

  int srow = tid >> 1;
  int shalf = tid & 1;
  int grow = min(r0 + srow, N - 1);

  auto load_stage = [&](int it, uint4& v0, uint4& v1){
    int k0 = it*32 + shalf*16;
    if constexpr (A_BF16){
      const ushort_t* Ab = (const ushort_t*)Ap;
      const uint4* ga = (const uint4*)(Ab + (size_t)grow*256 + k0);
      v0 = ga[0]; v1 = ga[1];
    } else {
      const float* Af = (const float*)Ap;
      const float4* ga = (const float4*)(Af + (size_t)grow*256 + k0);
      float4 f0 = ga[0], f1 = ga[1], f2 = ga[2], f3 = ga[3];
      v0.x = pk2bf(f0.x, f0.y); v0.y = pk2bf(f0.z, f0.w);
      v0.z = pk2bf(f1.x, f1.y); v0.w = pk2bf(f1.z, f1.w);
      v1.x = pk2bf(f2.x, f2.y); v1.y = pk2bf(f2.z, f2.w);
      v1.z = pk2bf(f3.x, f3.y); v1.w = pk2bf(f3.z, f3.w);
    }
  };
  auto write_stage = [&](int b, uint4 v0, uint4 v1){
    *(uint4*)&As[b][srow][shalf*16]     = v0;
    *(uint4*)&As[b][srow][shalf*16 + 8] = v1;
  };

  {
    uint4 v0, v1;
    load_stage(0, v0, v1);
    write_stage(0, v0, v1);
  }
  __syncthreads();

  #pragma unroll
  for (int it = 0; it < 8; it++){
    const int b = it & 1;
    uint4 n0, n1;
    if (it < 7) load_stage(it + 1, n0, n1);
    #pragma unroll
    for (int rt = 0; rt < 4; rt++){
      int arow = wr*64 + rt*16 + l15;
      uint4 av = *(const uint4*)&As[b][arow][quad*8];
      bf16x8 af = as_bf16x8(av);
      #pragma unroll
      for (int ct = 0; ct < 4; ct++)
        acc[rt][ct] = __builtin_amdgcn_mfma_f32_16x16x32_bf16(
            af, as_bf16x8(bfr[ct][it]), acc[rt][ct], 0, 0, 0);
    }
    if (it < 7){
      write_stage(b ^ 1, n0, n1);
      __syncthreads();
    }
  }

  // store C (fp8): row = r0+wr*64+rt*16+quad*4+g, col = cb*128+wc*64+ct*16+l15
  int crow0 = r0 + wr*64 + quad*4;
  int ccol0 = cb*128 + wc*64 + l15;
  #pragma unroll
  for (int rt = 0; rt < 4; rt++){
    #pragma unroll
    for (int g = 0; g < 4; g++){
      int row = crow0 + rt*16 + g;
      if (row < N){
        #pragma unroll
        for (int ct = 0; ct < 4; ct++)
          out[(size_t)row*256 + ccol0 + ct*16] = f2fp8(acc[rt][ct][g]);
      }
    }
  }
}

// ---------- GCN aggregation (fp8 gather -> bf16 out): half-wave (32 lanes) per
// node, 8 fp8 cols per lane as one 8B uint2 load (256B/row, fully coalesced).

__global__ __launch_bounds__(256) void agg_kernel(const unsigned char* __restrict__ xw,
                                                  const float* __restrict__ dis,
                                                  const int* __restrict__ rp,
                                                  const int* __restrict__ csrc,
                                                  const float* __restrict__ bias,
                                                  ushort_t* __restrict__ out, int N){
  int node = blockIdx.x*8 + (threadIdx.x >> 5);
  int lane = threadIdx.x & 31;
  if (node >= N) return;
  const uint2* xw2 = (const uint2*)xw;     // 8 B = 8 fp8; row = 32 uint2
  float di = dis[node];
  float sc = di * di;
  float acc[8];
  {
    uint2 a = xw2[(size_t)node*32 + lane];
    float v0,v1,v2,v3,v4,v5,v6,v7;
    fp8x4_to_f32(a.x, v0, v1, v2, v3);
    fp8x4_to_f32(a.y, v4, v5, v6, v7);
    acc[0]=v0*sc; acc[1]=v1*sc; acc[2]=v2*sc; acc[3]=v3*sc;
    acc[4]=v4*sc; acc[5]=v5*sc; acc[6]=v6*sc; acc[7]=v7*sc;
  }
  int e0 = rp[node], e1 = rp[node+1];
  for (int e = e0; e < e1; e++){
    int s = csrc[e];
    float cc = dis[s] * di;
    uint2 v = xw2[(size_t)s*32 + lane];
    float v0,v1,v2,v3,v4,v5,v6,v7;
    fp8x4_to_f32(v.x, v0, v1, v2, v3);
    fp8x4_to_f32(v.y, v4, v5, v6, v7);
    acc[0] = fmaf(v0, cc, acc[0]);
    acc[1] = fmaf(v1, cc, acc[1]);
    acc[2] = fmaf(v2, cc, acc[2]);
    acc[3] = fmaf(v3, cc, acc[3]);
    acc[4] = fmaf(v4, cc, acc[4]);
    acc[5] = fmaf(v5, cc, acc[5]);
    acc[6] = fmaf(v6, cc, acc[6]);
    acc[7] = fmaf(v7, cc, acc[7]);
  }
  const float4* b4 = (const float4*)bias;   // cols lane*8..lane*8+7
  float4 bA = b4[lane*2], bB = b4[lane*2+1];
  acc[0] = fmaxf(acc[0] + bA.x, 0.f);
  acc[1] = fmaxf(acc[1] + bA.y, 0.f);
  acc[2] = fmaxf(acc[2] + bA.z, 0.f);
  acc[3] = fmaxf(acc[3] + bA.w, 0.f);
  acc[4] = fmaxf(acc[4] + bB.x, 0.f);
  acc[5] = fmaxf(acc[5] + bB.y, 0.f);
  acc[6] = fmaxf(acc[6] + bB.z, 0.f);
  acc[7] = fmaxf(acc[7] + bB.w, 0.f);
  uint4 o;
  o.x = pk2bf(acc[0], acc[1]);
  o.y = pk2bf(acc[2], acc[3]);
  o.z = pk2bf(acc[4], acc[5]);
  o.w = pk2bf(acc[6], acc[7]);
  ((uint4*)out)[(size_t)node*32 + lane] = o;
}

// ---------- mean pool (bf16 input, fp32 accumulate) ----------

__global__ void pool_kernel(const ushort_t* __restrict__ h, const int* __restrict__ ptr,
                            float* __restrict__ hp){
  int t = blockIdx.x; int part = blockIdx.y; int c = threadIdx.x;
  int s0 = ptr[t], s1 = ptr[t+1];
  int len = s1 - s0;
  int chunk = (len + 7) / 8;
  int r0 = s0 + part*chunk;
  int r1 = min(r0 + chunk, s1);
  float acc = 0.f;
  for (int r = r0; r < r1; r++) acc += bf2f(h[(size_t)r*256 + c]);
  if (r1 > r0) atomicAdd(&hp[t*256 + c], acc);
}

// ---------- GX[t,g] = dot(hp[t]/cnt[t], w_ih[g]) + b_ih[g] (+ b_hh[g] for r,z
// gates, folded here so the GRU loop carries 2 fewer live VGPRs) ----------

__global__ __launch_bounds__(768) void gx_kernel(const float* __restrict__ hp,
                                                 const int* __restrict__ ptr,
                                                 const float* __restrict__ wih,
                                                 const float* __restrict__ bih,
                                                 const float* __restrict__ bhh,
                                                 float* __restrict__ gx){
  __shared__ float xs[256];
  int t = blockIdx.x; int g = threadIdx.x;
  if (g < 256){
    float cf = (float)max(ptr[t+1] - ptr[t], 1);
    xs[g] = hp[t*256 + g] / cf;
  }
  __syncthreads();
  float acc = bih[g] + (g < 512 ? bhh[g] : 0.f);
  const float* wr = wih + (size_t)g*256;
  #pragma unroll 4
  for (int k = 0; k < 256; k++) acc = fmaf(xs[k], wr[k], acc);
  gx[t*768 + g] = acc;
}

// ---------- sequential GRU: single block, 1024 threads (4 threads/gate),
// w_hh register-resident f16 (96 VGPRs), double-buffered h in LDS -> ONE
// barrier per step, next-step gx prefetched, native exp/rcp transcendentals.
// VGPR budget: amdgpu_waves_per_eu(4,4) pins exactly 4 waves/EU (the 16-wave
// block) -> 512/4 = 128-VGPR cap. (__launch_bounds__ 2nd arg proved unreliable:
// (1024,4) measured a 64-VGPR cap and spilled all weights -> 320KB scratch.)

__device__ inline float fast_sig(float x){
  return __builtin_amdgcn_rcpf(1.f + __expf(-x));
}
__device__ inline float fast_tanh(float x){
  // 1 - 2/(e^{2x}+1); exact limits at +-inf via rcp(inf)=0
  return 1.f - 2.f*__builtin_amdgcn_rcpf(1.f + __expf(2.f*x));
}

__global__ __launch_bounds__(1024)
__attribute__((amdgpu_waves_per_eu(4, 4)))
void gru_kernel(const float* __restrict__ gx,
                const float* __restrict__ whh,
                const float* __restrict__ bhh,
                const float* __restrict__ Wc,
                const float* __restrict__ bc,
                float* __restrict__ out){
  __shared__ _Float16 hh[2][256];
  __shared__ float hfin[256];
  int tid = threadIdx.x;
  int i = tid >> 2;        // gate index 0..255
  int q = tid & 3;         // k-quarter (64 floats = 32 h2 each)

  h2_t wrg[32], wzg[32], wng[32];
  {
    const float2* w2 = (const float2*)whh;
    size_t base = (size_t)q * 32;
    const float2* pr = w2 + (size_t)i*128       + base;
    const float2* pz = w2 + (size_t)(i+256)*128 + base;
    const float2* pn = w2 + (size_t)(i+512)*128 + base;
    #pragma unroll
    for (int k = 0; k < 32; k++){
      float2 a = pr[k];
      float2 b = pz[k];
      float2 c = pn[k];
      wrg[k] = h2_t{(_Float16)a.x, (_Float16)a.y};
      wzg[k] = h2_t{(_Float16)b.x, (_Float16)b.y};
      wng[k] = h2_t{(_Float16)c.x, (_Float16)c.y};
    }
  }
  float bN = bhh[i + 512];           // r,z biases folded into gx upstream
  if (tid < 256) hh[0][tid] = (_Float16)0.f;
  float h = 0.f;
  // prefetch t=0 gx
  float gxr = gx[i], gxz = gx[256 + i], gxn = gx[512 + i];
  __syncthreads();

  for (int t = 0; t < 64; t++){
    // prefetch next step's gx; consumed after this step's compute
    float ngr = 0.f, ngz = 0.f, ngn = 0.f;
    if (t < 63){
      const float* g = gx + (size_t)(t+1)*768;
      ngr = g[i]; ngz = g[256 + i]; ngn = g[512 + i];
    }
    const h2_t* hp2 = ((const h2_t*)hh[t & 1]) + q*32;
    float aR0=0.f, aR1=0.f, aZ0=0.f, aZ1=0.f, aN0=0.f, aN1=0.f;
    #pragma unroll
    for (int k = 0; k < 32; k += 2){
      h2_t h0 = hp2[k];
      h2_t h1 = hp2[k+1];
#ifdef HAS_FDOT2
      aR0 = __builtin_amdgcn_fdot2(h0, wrg[k],   aR0, false);
      aZ0 = __builtin_amdgcn_fdot2(h0, wzg[k],   aZ0, false);
      aN0 = __builtin_amdgcn_fdot2(h0, wng[k],   aN0, false);
      aR1 = __builtin_amdgcn_fdot2(h1, wrg[k+1], aR1, false);
      aZ1 = __builtin_amdgcn_fdot2(h1, wzg[k+1], aZ1, false);
      aN1 = __builtin_amdgcn_fdot2(h1, wng[k+1], aN1, false);
#else
      aR0 = fmaf((float)h0.x, (float)wrg[k].x, aR0);
      aR0 = fmaf((float)h0.y, (float)wrg[k].y, aR0);
      aZ0 = fmaf((float)h0.x, (float)wzg[k].x, aZ0);
      aZ0 = fmaf((float)h0.y, (float)wzg[k].y, aZ0);
      aN0 = fmaf((float)h0.x, (float)wng[k].x, aN0);
      aN0 = fmaf((float)h0.y, (float)wng[k].y, aN0);
      aR1 = fmaf((float)h1.x, (float)wrg[k+1].x, aR1);
      aR1 = fmaf((float)h1.y, (float)wrg[k+1].y, aR1);
      aZ1 = fmaf((float)h1.x, (float)wzg[k+1].x, aZ1);
      aZ1 = fmaf((float)h1.y, (float)wzg[k+1].y, aZ1);
      aN1 = fmaf((float)h1.x, (float)wng[k+1].x, aN1);
      aN1 = fmaf((float)h1.y, (float)wng[k+1].y, aN1);
#endif
    }
    float accR = aR0 + aR1, accZ = aZ0 + aZ1, accN = aN0 + aN1;
    accR += __shfl_xor(accR, 1); accR += __shfl_xor(accR, 2);
    accZ += __shfl_xor(accZ, 1); accZ += __shfl_xor(accZ, 2);
    accN += __shfl_xor(accN, 1); accN += __shfl_xor(accN, 2);
    float r = fast_sig(gxr + accR);
    float z = fast_sig(gxz + accZ);
    float n = fast_tanh(gxn + r*(accN + bN));
    float hnew = (1.f - z)*n + z*h;
    if (q == 0) hh[(t & 1) ^ 1][i] = (_Float16)hnew;
    gxr = ngr; gxz = ngz; gxn = ngn;
    h = hnew;
    __syncthreads();
  }

  if (q == 0) hfin[i] = h;
  __syncthreads();
  if (tid < 64){
    int r = tid >> 2, qq = tid & 3;
    const float4* wrow = (const float4*)(Wc + (size_t)r*256 + (size_t)qq*64);
    const float4* hv = (const float4*)(hfin + (size_t)qq*64);
    float acc = 0.f;
    #pragma unroll
    for (int k = 0; k < 16; k++){
      float4 wv = wrow[k];
      float4 xv = hv[k];
      acc = fmaf(wv.x, xv.x, acc);
      acc = fmaf(wv.y, xv.y, acc);
      acc = fmaf(wv.z, xv.z, acc);
      acc = fmaf(wv.w, xv.w, acc);
    }
    acc += __shfl_xor(acc, 1);
    acc += __shfl_xor(acc, 2);
    if (qq == 0) out[r] = acc + bc[r];
  }
}

extern "C" void kernel_launch(void* const* d_in, const int* in_sizes, int n_in,
                              void* d_out, int out_size, void* d_ws, size_t ws_size,
                              hipStream_t stream){
  const float* x   = (const float*)d_in[0];
  const int*   ei  = (const int*)d_in[1];
  const int*   ptr = (const int*)d_in[2];
  const float* W1  = (const float*)d_in[3];
  const float* b1  = (const float*)d_in[4];
  const float* W2  = (const float*)d_in[5];
  const float* b2  = (const float*)d_in[6];
  const float* wih = (const float*)d_in[7];
  const float* whh = (const float*)d_in[8];
  const float* bih = (const float*)d_in[9];
  const float* bhh = (const float*)d_in[10];
  const float* Wc  = (const float*)d_in[11];
  const float* bc  = (const float*)d_in[12];
  float* outp = (float*)d_out;

  const int N = in_sizes[0] / 256;   // 100000
  const int E = in_sizes[1] / 2;     // 1600000

  char* w = (char*)d_ws;
  size_t off = 0;
  auto alloc = [&](size_t bytes){ void* p = w + off; off = align512(off + bytes); return p; };
  unsigned char* bufA = (unsigned char*)alloc((size_t)N*256);     // xw (fp8 e4m3)
  ushort_t*      bufB = (ushort_t*)alloc((size_t)N*256*2);        // h  (bf16)
  float* dis  = (float*)alloc((size_t)N*4);
  int*   cnt  = (int*)  alloc((size_t)N*4);
  int*   rp   = (int*)  alloc((size_t)(N+1)*4);
  int*   bsum = (int*)  alloc(128*4);
  int*   csrc = (int*)  alloc((size_t)E*4);
  uint4* Wp1  = (uint4*)alloc(8192*16);
  uint4* Wp2  = (uint4*)alloc(8192*16);
  float* hp   = (float*)alloc((size_t)64*256*4);
  float* gxb  = (float*)alloc((size_t)64*768*4);
  (void)ws_size; (void)n_in; (void)out_size;

  hipMemsetAsync(cnt, 0, (size_t)N*4, stream);
  hipMemsetAsync(hp,  0, (size_t)64*256*4, stream);

  // CSR build + degree + weight packing
  count_kernel<<<(E+255)/256, 256, 0, stream>>>(ei, cnt, E);
  dis_kernel<<<(N+255)/256, 256, 0, stream>>>(cnt, dis, N);
  int nb = (N + 1023) / 1024;
  scan_block_kernel<<<nb, 1024, 0, stream>>>(cnt, rp, bsum, N);
  scan_sums_kernel<<<1, 128, 0, stream>>>(bsum, nb);
  add_off_kernel<<<(N+255)/256, 256, 0, stream>>>(rp, bsum, cnt, N);
  fill_kernel<<<(E+255)/256, 256, 0, stream>>>(ei, rp, cnt, csrc, E);
  packW_kernel<<<32, 256, 0, stream>>>(W1, Wp1);
  packW_kernel<<<32, 256, 0, stream>>>(W2, Wp2);

  // GCN layer 1
  gemm_mfma<false><<<dim3((N+127)/128, 2), 256, 0, stream>>>(x, Wp1, bufA, N);
  agg_kernel<<<(N+7)/8, 256, 0, stream>>>(bufA, dis, rp, csrc, b1, bufB, N);
  // GCN layer 2
  gemm_mfma<true><<<dim3((N+127)/128, 2), 256, 0, stream>>>(bufB, Wp2, bufA, N);
  agg_kernel<<<(N+7)/8, 256, 0, stream>>>(bufA, dis, rp, csrc, b2, bufB, N);

  // pool + GRU + classifier
  pool_kernel<<<dim3(64, 8), 256, 0, stream>>>(bufB, ptr, hp);
  gx_kernel<<<64, 768, 0, stream>>>(hp, ptr, wih, bih, bhh, gxb);
  gru_kernel<<<1, 1024, 0, stream>>>(gxb, whh, bhh, Wc, bc, outp);
}

// Round 4
// 835.632 us; speedup vs baseline: 1.0040x; 1.0008x over previous
//
#include <hip/hip_runtime.h>
#include <hip/hip_bf16.h>
#include <math.h>

// Problem constants (fixed by reference): N=100000 nodes, E=1.6M edges, H=256, T=64.

static inline size_t align512(size_t x){ return (x + 511) & ~size_t(511); }

typedef _Float16 h2_t __attribute__((ext_vector_type(2)));
typedef unsigned short ushort_t;
typedef short bf16x8 __attribute__((ext_vector_type(8)));   // 8 bf16 = 4 VGPRs (MFMA A/B frag)
typedef float f32x4 __attribute__((ext_vector_type(4)));    // MFMA C/D frag
typedef float f32x2 __attribute__((ext_vector_type(2)));

#if defined(__has_builtin)
#if __has_builtin(__builtin_amdgcn_fdot2)
#define HAS_FDOT2 1
#endif
#if __has_builtin(__builtin_amdgcn_cvt_pk_f32_fp8) && __has_builtin(__builtin_amdgcn_cvt_pk_fp8_f32)
#define HAS_FP8CVT 1
#endif
#endif

__device__ inline ushort_t f2bf(float f){
  unsigned u = __float_as_uint(f);
  unsigned r = u + 0x7FFFu + ((u >> 16) & 1u);   // RTNE
  return (ushort_t)(r >> 16);
}
__device__ inline float bf2f(ushort_t h){ return __uint_as_float(((unsigned)h) << 16); }
__device__ inline unsigned pk2bf(float lo, float hi){
  return ((unsigned)f2bf(hi) << 16) | (unsigned)f2bf(lo);
}
__device__ inline bf16x8 as_bf16x8(uint4 u){
  union { uint4 u4; bf16x8 b; } c; c.u4 = u; return c.b;
}

// ---- fp8 e4m3 encode/decode (HW cvt on gfx950; SW fallback approximate) ----

__device__ inline unsigned char f2fp8(float x){
#ifdef HAS_FP8CVT
  int p = __builtin_amdgcn_cvt_pk_fp8_f32(x, x, 0, false);
  return (unsigned char)(p & 0xFF);
#else
  unsigned u = __float_as_uint(x);
  unsigned s = (u >> 24) & 0x80u;
  unsigned um = u & 0x7FFFFFFFu;
  if (um >= 0x43E00000u) return (unsigned char)(s | 0x7E);      // clamp to 448
  if (um <  0x3C000000u) return (unsigned char)s;               // flush < 2^-7
  unsigned r = um + 0x7FFFFu + ((um >> 20) & 1u);               // RTNE at bit 20
  unsigned e = (r >> 23) & 0xFF, m = (r >> 20) & 7u;
  return (unsigned char)(s | ((e - 120u) << 3) | m);
#endif
}
__device__ inline void fp8x4_to_f32(unsigned v, float& a, float& b, float& c, float& d){
#ifdef HAS_FP8CVT
  f32x2 lo = __builtin_amdgcn_cvt_pk_f32_fp8(v, false);
  f32x2 hi = __builtin_amdgcn_cvt_pk_f32_fp8(v, true);
  a = lo.x; b = lo.y; c = hi.x; d = hi.y;
#else
  auto d1 = [](unsigned char t)->float{
    unsigned s = (t >> 7) & 1u, e = (t >> 3) & 0xFu, m = t & 7u;
    float v = (e == 0) ? ldexpf((float)m, -9) : ldexpf(8.0f + (float)m, (int)e - 10);
    return s ? -v : v;
  };
  a = d1(v & 0xFF); b = d1((v >> 8) & 0xFF); c = d1((v >> 16) & 0xFF); d = d1(v >> 24);
#endif
}

// ---------- CSR build ----------

__global__ void count_kernel(const int* __restrict__ ei, int* __restrict__ cnt, int E){
  int e = blockIdx.x*256 + threadIdx.x;
  if (e < E) atomicAdd(&cnt[ei[E + e]], 1);
}

__global__ void dis_kernel(const int* __restrict__ cnt, float* __restrict__ dis, int N){
  int i = blockIdx.x*256 + threadIdx.x;
  if (i < N) dis[i] = rsqrtf((float)cnt[i] + 1.0f);
}

__global__ void scan_block_kernel(const int* __restrict__ cnt, int* __restrict__ rp,
                                  int* __restrict__ bsum, int N){
  __shared__ int s[2][1024];
  int t = threadIdx.x; int i = blockIdx.x*1024 + t;
  int v = (i < N) ? cnt[i] : 0;
  int cur = 0; s[0][t] = v; __syncthreads();
  for (int off = 1; off < 1024; off <<= 1){
    int nxt = cur ^ 1;
    int val = s[cur][t];
    if (t >= off) val += s[cur][t - off];
    s[nxt][t] = val; cur = nxt; __syncthreads();
  }
  if (i < N) rp[i+1] = s[cur][t];
  if (t == 1023) bsum[blockIdx.x] = s[cur][1023];
}

__global__ void scan_sums_kernel(int* __restrict__ bsum, int nb){
  __shared__ int s[128];
  int t = threadIdx.x;
  if (t < nb) s[t] = bsum[t];
  __syncthreads();
  if (t == 0){ int acc = 0; for (int b = 0; b < nb; b++){ int v = s[b]; s[b] = acc; acc += v; } }
  __syncthreads();
  if (t < nb) bsum[t] = s[t];
}

__global__ void add_off_kernel(int* __restrict__ rp, const int* __restrict__ bsum,
                               int* __restrict__ cnt, int N){
  int i = blockIdx.x*256 + threadIdx.x;
  if (i < N){ rp[i+1] += bsum[i >> 10]; cnt[i] = 0; }
  if (i == 0) rp[0] = 0;
}

__global__ void fill_kernel(const int* __restrict__ ei, const int* __restrict__ rp,
                            int* __restrict__ cnt, int* __restrict__ csrc, int E){
  int e = blockIdx.x*256 + threadIdx.x;
  if (e < E){
    int s = ei[e]; int d = ei[E + e];
    int pos = rp[d] + atomicAdd(&cnt[d], 1);
    csrc[pos] = s;
  }
}

// ---------- pack W (256x256 fp32 [k][n]) into MFMA B-fragment order (bf16) ----------

__global__ void packW_kernel(const float* __restrict__ W, uint4* __restrict__ Wp){
  int idx = blockIdx.x*256 + threadIdx.x;    // 0..8191
  int lane = idx & 63;
  int blk  = idx >> 6;                        // 0..127
  int q    = blk & 7;
  int t16  = blk >> 3;                        // 0..15 (16-col group)
  int n = t16*16 + (lane & 15);
  int k = q*32 + (lane >> 4)*8;
  uint4 v;
  v.x = pk2bf(W[(size_t)(k+0)*256 + n], W[(size_t)(k+1)*256 + n]);
  v.y = pk2bf(W[(size_t)(k+2)*256 + n], W[(size_t)(k+3)*256 + n]);
  v.z = pk2bf(W[(size_t)(k+4)*256 + n], W[(size_t)(k+5)*256 + n]);
  v.w = pk2bf(W[(size_t)(k+6)*256 + n], W[(size_t)(k+7)*256 + n]);
  Wp[idx] = v;
}

// ---------- MFMA GEMM: out[N,256](fp8 e4m3) = A[N,256] @ W[256,256] ----------
// 128x128 tile, 4 waves (2x2), each wave 64x64 via 4x4 tiles of 16x16x32 MFMA.
// B register-resident (128 VGPRs). A double-buffered in LDS. Out stored fp8
// (the consumer is the edge-gather, which is fabric-bytes-bound).

template<bool A_BF16>
__global__ __launch_bounds__(256, 2) void gemm_mfma(const void* __restrict__ Ap,
                                                    const uint4* __restrict__ Wp,
                                                    unsigned char* __restrict__ out, int N){
  __shared__ __align__(16) ushort_t As[2][128][40];
  int tid  = threadIdx.x;
  int lane = tid & 63;
  int wave = tid >> 6;
  int wr = wave >> 1, wc = wave & 1;
  int quad = lane >> 4;
  int l15  = lane & 15;
  int r0 = blockIdx.x * 128;
  int cb = blockIdx.y;

  uint4 bfr[4][8];
  {
    const uint4* wpb = Wp + (size_t)(cb*2 + wc) * 2048;
    #pragma unroll
    for (int ct = 0; ct < 4; ct++)
      #pragma unroll
      for (int q = 0; q < 8; q++)
        bfr[ct][q] = wpb[(ct*8 + q)*64 + lane];
  }

  f32x4 acc[4][4];
  #pragma unroll
  for (int rt = 0; rt < 4; rt++)
    #pragma unroll
    for (int ct = 0; ct < 4; ct++)
      acc[rt][ct] = f32x4{0.f, 0.f, 0.f, 0.f};

  int srow = tid >> 1;
  int shalf = tid & 1;
  int grow = min(r0 + srow, N - 1);

  auto load_stage = [&](int it, uint4& v0, uint4& v1){
    int k0 = it*32 + shalf*16;
    if constexpr (A_BF16){
      const ushort_t* Ab = (const ushort_t*)Ap;
      const uint4* ga = (const uint4*)(Ab + (size_t)grow*256 + k0);
      v0 = ga[0]; v1 = ga[1];
    } else {
      const float* Af = (const float*)Ap;
      const float4* ga = (const float4*)(Af + (size_t)grow*256 + k0);
      float4 f0 = ga[0], f1 = ga[1], f2 = ga[2], f3 = ga[3];
      v0.x = pk2bf(f0.x, f0.y); v0.y = pk2bf(f0.z, f0.w);
      v0.z = pk2bf(f1.x, f1.y); v0.w = pk2bf(f1.z, f1.w);
      v1.x = pk2bf(f2.x, f2.y); v1.y = pk2bf(f2.z, f2.w);
      v1.z = pk2bf(f3.x, f3.y); v1.w = pk2bf(f3.z, f3.w);
    }
  };
  auto write_stage = [&](int b, uint4 v0, uint4 v1){
    *(uint4*)&As[b][srow][shalf*16]     = v0;
    *(uint4*)&As[b][srow][shalf*16 + 8] = v1;
  };

  {
    uint4 v0, v1;
    load_stage(0, v0, v1);
    write_stage(0, v0, v1);
  }
  __syncthreads();

  #pragma unroll
  for (int it = 0; it < 8; it++){
    const int b = it & 1;
    uint4 n0, n1;
    if (it < 7) load_stage(it + 1, n0, n1);
    #pragma unroll
    for (int rt = 0; rt < 4; rt++){
      int arow = wr*64 + rt*16 + l15;
      uint4 av = *(const uint4*)&As[b][arow][quad*8];
      bf16x8 af = as_bf16x8(av);
      #pragma unroll
      for (int ct = 0; ct < 4; ct++)
        acc[rt][ct] = __builtin_amdgcn_mfma_f32_16x16x32_bf16(
            af, as_bf16x8(bfr[ct][it]), acc[rt][ct], 0, 0, 0);
    }
    if (it < 7){
      write_stage(b ^ 1, n0, n1);
      __syncthreads();
    }
  }

  // store C (fp8): row = r0+wr*64+rt*16+quad*4+g, col = cb*128+wc*64+ct*16+l15
  int crow0 = r0 + wr*64 + quad*4;
  int ccol0 = cb*128 + wc*64 + l15;
  #pragma unroll
  for (int rt = 0; rt < 4; rt++){
    #pragma unroll
    for (int g = 0; g < 4; g++){
      int row = crow0 + rt*16 + g;
      if (row < N){
        #pragma unroll
        for (int ct = 0; ct < 4; ct++)
          out[(size_t)row*256 + ccol0 + ct*16] = f2fp8(acc[rt][ct][g]);
      }
    }
  }
}

// ---------- GCN aggregation (fp8 gather -> bf16 out): half-wave (32 lanes) per
// node, 8 fp8 cols per lane as one 8B uint2 load (256B/row, fully coalesced).

__global__ __launch_bounds__(256) void agg_kernel(const unsigned char* __restrict__ xw,
                                                  const float* __restrict__ dis,
                                                  const int* __restrict__ rp,
                                                  const int* __restrict__ csrc,
                                                  const float* __restrict__ bias,
                                                  ushort_t* __restrict__ out, int N){
  int node = blockIdx.x*8 + (threadIdx.x >> 5);
  int lane = threadIdx.x & 31;
  if (node >= N) return;
  const uint2* xw2 = (const uint2*)xw;     // 8 B = 8 fp8; row = 32 uint2
  float di = dis[node];
  float sc = di * di;
  float acc[8];
  {
    uint2 a = xw2[(size_t)node*32 + lane];
    float v0,v1,v2,v3,v4,v5,v6,v7;
    fp8x4_to_f32(a.x, v0, v1, v2, v3);
    fp8x4_to_f32(a.y, v4, v5, v6, v7);
    acc[0]=v0*sc; acc[1]=v1*sc; acc[2]=v2*sc; acc[3]=v3*sc;
    acc[4]=v4*sc; acc[5]=v5*sc; acc[6]=v6*sc; acc[7]=v7*sc;
  }
  int e0 = rp[node], e1 = rp[node+1];
  for (int e = e0; e < e1; e++){
    int s = csrc[e];
    float cc = dis[s] * di;
    uint2 v = xw2[(size_t)s*32 + lane];
    float v0,v1,v2,v3,v4,v5,v6,v7;
    fp8x4_to_f32(v.x, v0, v1, v2, v3);
    fp8x4_to_f32(v.y, v4, v5, v6, v7);
    acc[0] = fmaf(v0, cc, acc[0]);
    acc[1] = fmaf(v1, cc, acc[1]);
    acc[2] = fmaf(v2, cc, acc[2]);
    acc[3] = fmaf(v3, cc, acc[3]);
    acc[4] = fmaf(v4, cc, acc[4]);
    acc[5] = fmaf(v5, cc, acc[5]);
    acc[6] = fmaf(v6, cc, acc[6]);
    acc[7] = fmaf(v7, cc, acc[7]);
  }
  const float4* b4 = (const float4*)bias;   // cols lane*8..lane*8+7
  float4 bA = b4[lane*2], bB = b4[lane*2+1];
  acc[0] = fmaxf(acc[0] + bA.x, 0.f);
  acc[1] = fmaxf(acc[1] + bA.y, 0.f);
  acc[2] = fmaxf(acc[2] + bA.z, 0.f);
  acc[3] = fmaxf(acc[3] + bA.w, 0.f);
  acc[4] = fmaxf(acc[4] + bB.x, 0.f);
  acc[5] = fmaxf(acc[5] + bB.y, 0.f);
  acc[6] = fmaxf(acc[6] + bB.z, 0.f);
  acc[7] = fmaxf(acc[7] + bB.w, 0.f);
  uint4 o;
  o.x = pk2bf(acc[0], acc[1]);
  o.y = pk2bf(acc[2], acc[3]);
  o.z = pk2bf(acc[4], acc[5]);
  o.w = pk2bf(acc[6], acc[7]);
  ((uint4*)out)[(size_t)node*32 + lane] = o;
}

// ---------- mean pool (bf16 input, fp32 accumulate) ----------

__global__ void pool_kernel(const ushort_t* __restrict__ h, const int* __restrict__ ptr,
                            float* __restrict__ hp){
  int t = blockIdx.x; int part = blockIdx.y; int c = threadIdx.x;
  int s0 = ptr[t], s1 = ptr[t+1];
  int len = s1 - s0;
  int chunk = (len + 7) / 8;
  int r0 = s0 + part*chunk;
  int r1 = min(r0 + chunk, s1);
  float acc = 0.f;
  for (int r = r0; r < r1; r++) acc += bf2f(h[(size_t)r*256 + c]);
  if (r1 > r0) atomicAdd(&hp[t*256 + c], acc);
}

// ---------- GX[t,g] = dot(hp[t]/cnt[t], w_ih[g]) + b_ih[g] (+ b_hh[g] for r,z
// gates, folded here so the GRU loop carries 2 fewer live VGPRs) ----------

__global__ __launch_bounds__(768) void gx_kernel(const float* __restrict__ hp,
                                                 const int* __restrict__ ptr,
                                                 const float* __restrict__ wih,
                                                 const float* __restrict__ bih,
                                                 const float* __restrict__ bhh,
                                                 float* __restrict__ gx){
  __shared__ float xs[256];
  int t = blockIdx.x; int g = threadIdx.x;
  if (g < 256){
    float cf = (float)max(ptr[t+1] - ptr[t], 1);
    xs[g] = hp[t*256 + g] / cf;
  }
  __syncthreads();
  float acc = bih[g] + (g < 512 ? bhh[g] : 0.f);
  const float* wr = wih + (size_t)g*256;
  #pragma unroll 4
  for (int k = 0; k < 256; k++) acc = fmaf(xs[k], wr[k], acc);
  gx[t*768 + g] = acc;
}

// ---------- sequential GRU: single block, 512 threads (2 threads/gate),
// w_hh register-resident f16 (96 VGPRs). (512,2) is the PROVEN register
// shape: round-0 measured VGPR=128, no spill. 1024-thread variants were
// force-capped to 64 VGPR by the allocator on this toolchain (3 rounds,
// identical 320KB spill traces) -- do not revisit.
// This round's deltas vs round 0: double-buffered hh -> ONE barrier/step
// (was 2), next-step gx prefetch, native exp/rcp transcendentals, r/z
// biases folded into gx, __align__(16) LDS for ds_read_b128 h loads,
// split accumulator chains.

__device__ inline float fast_sig(float x){
  return __builtin_amdgcn_rcpf(1.f + __expf(-x));
}
__device__ inline float fast_tanh(float x){
  // 1 - 2/(e^{2x}+1); exact limits at +-inf via rcp(inf)=0
  return 1.f - 2.f*__builtin_amdgcn_rcpf(1.f + __expf(2.f*x));
}

__global__ __launch_bounds__(512, 2) void gru_kernel(const float* __restrict__ gx,
                                                     const float* __restrict__ whh,
                                                     const float* __restrict__ bhh,
                                                     const float* __restrict__ Wc,
                                                     const float* __restrict__ bc,
                                                     float* __restrict__ out){
  __shared__ __align__(16) _Float16 hh[2][256];
  __shared__ float hfin[256];
  int tid = threadIdx.x;
  int i = tid >> 1;        // gate index 0..255
  int half = tid & 1;      // k-half (128 floats = 64 h2)

  h2_t wr[64], wz[64], wn[64];
  {
    const float2* w2 = (const float2*)whh;
    size_t base = (size_t)half * 64;
    const float2* pr = w2 + (size_t)i*128       + base;
    const float2* pz = w2 + (size_t)(i+256)*128 + base;
    const float2* pn = w2 + (size_t)(i+512)*128 + base;
    #pragma unroll
    for (int k = 0; k < 64; k++){
      float2 a = pr[k];
      float2 b = pz[k];
      float2 c = pn[k];
      wr[k] = h2_t{(_Float16)a.x, (_Float16)a.y};
      wz[k] = h2_t{(_Float16)b.x, (_Float16)b.y};
      wn[k] = h2_t{(_Float16)c.x, (_Float16)c.y};
    }
  }
  float bN = bhh[i + 512];           // r,z biases folded into gx upstream
  if (tid < 256) hh[0][tid] = (_Float16)0.f;
  float h = 0.f;
  // prefetch t=0 gx
  float gxr = gx[i], gxz = gx[256 + i], gxn = gx[512 + i];
  __syncthreads();

  for (int t = 0; t < 64; t++){
    // prefetch next step's gx; consumed after this step's compute
    float ngr = 0.f, ngz = 0.f, ngn = 0.f;
    if (t < 63){
      const float* g = gx + (size_t)(t+1)*768;
      ngr = g[i]; ngz = g[256 + i]; ngn = g[512 + i];
    }
    const h2_t* hp2 = ((const h2_t*)hh[t & 1]) + half*64;
    float aR0=0.f, aR1=0.f, aZ0=0.f, aZ1=0.f, aN0=0.f, aN1=0.f;
    #pragma unroll
    for (int k = 0; k < 64; k += 2){
      h2_t h0 = hp2[k];
      h2_t h1 = hp2[k+1];
#ifdef HAS_FDOT2
      aR0 = __builtin_amdgcn_fdot2(h0, wr[k],   aR0, false);
      aZ0 = __builtin_amdgcn_fdot2(h0, wz[k],   aZ0, false);
      aN0 = __builtin_amdgcn_fdot2(h0, wn[k],   aN0, false);
      aR1 = __builtin_amdgcn_fdot2(h1, wr[k+1], aR1, false);
      aZ1 = __builtin_amdgcn_fdot2(h1, wz[k+1], aZ1, false);
      aN1 = __builtin_amdgcn_fdot2(h1, wn[k+1], aN1, false);
#else
      aR0 = fmaf((float)h0.x, (float)wr[k].x, aR0);
      aR0 = fmaf((float)h0.y, (float)wr[k].y, aR0);
      aZ0 = fmaf((float)h0.x, (float)wz[k].x, aZ0);
      aZ0 = fmaf((float)h0.y, (float)wz[k].y, aZ0);
      aN0 = fmaf((float)h0.x, (float)wn[k].x, aN0);
      aN0 = fmaf((float)h0.y, (float)wn[k].y, aN0);
      aR1 = fmaf((float)h1.x, (float)wr[k+1].x, aR1);
      aR1 = fmaf((float)h1.y, (float)wr[k+1].y, aR1);
      aZ1 = fmaf((float)h1.x, (float)wz[k+1].x, aZ1);
      aZ1 = fmaf((float)h1.y, (float)wz[k+1].y, aZ1);
      aN1 = fmaf((float)h1.x, (float)wn[k+1].x, aN1);
      aN1 = fmaf((float)h1.y, (float)wn[k+1].y, aN1);
#endif
    }
    float accR = aR0 + aR1, accZ = aZ0 + aZ1, accN = aN0 + aN1;
    accR += __shfl_xor(accR, 1);
    accZ += __shfl_xor(accZ, 1);
    accN += __shfl_xor(accN, 1);
    float r = fast_sig(gxr + accR);
    float z = fast_sig(gxz + accZ);
    float n = fast_tanh(gxn + r*(accN + bN));
    float hnew = (1.f - z)*n + z*h;
    if (half == 0) hh[(t & 1) ^ 1][i] = (_Float16)hnew;
    gxr = ngr; gxz = ngz; gxn = ngn;
    h = hnew;
    __syncthreads();
  }

  if (half == 0) hfin[i] = h;
  __syncthreads();
  if (tid < 64){
    int r = tid >> 2, qq = tid & 3;
    const float4* wrow = (const float4*)(Wc + (size_t)r*256 + (size_t)qq*64);
    const float4* hv = (const float4*)(hfin + (size_t)qq*64);
    float acc = 0.f;
    #pragma unroll
    for (int k = 0; k < 16; k++){
      float4 wv = wrow[k];
      float4 xv = hv[k];
      acc = fmaf(wv.x, xv.x, acc);
      acc = fmaf(wv.y, xv.y, acc);
      acc = fmaf(wv.z, xv.z, acc);
      acc = fmaf(wv.w, xv.w, acc);
    }
    acc += __shfl_xor(acc, 1);
    acc += __shfl_xor(acc, 2);
    if (qq == 0) out[r] = acc + bc[r];
  }
}

extern "C" void kernel_launch(void* const* d_in, const int* in_sizes, int n_in,
                              void* d_out, int out_size, void* d_ws, size_t ws_size,
                              hipStream_t stream){
  const float* x   = (const float*)d_in[0];
  const int*   ei  = (const int*)d_in[1];
  const int*   ptr = (const int*)d_in[2];
  const float* W1  = (const float*)d_in[3];
  const float* b1  = (const float*)d_in[4];
  const float* W2  = (const float*)d_in[5];
  const float* b2  = (const float*)d_in[6];
  const float* wih = (const float*)d_in[7];
  const float* whh = (const float*)d_in[8];
  const float* bih = (const float*)d_in[9];
  const float* bhh = (const float*)d_in[10];
  const float* Wc  = (const float*)d_in[11];
  const float* bc  = (const float*)d_in[12];
  float* outp = (float*)d_out;

  const int N = in_sizes[0] / 256;   // 100000
  const int E = in_sizes[1] / 2;     // 1600000

  char* w = (char*)d_ws;
  size_t off = 0;
  auto alloc = [&](size_t bytes){ void* p = w + off; off = align512(off + bytes); return p; };
  unsigned char* bufA = (unsigned char*)alloc((size_t)N*256);     // xw (fp8 e4m3)
  ushort_t*      bufB = (ushort_t*)alloc((size_t)N*256*2);        // h  (bf16)
  float* dis  = (float*)alloc((size_t)N*4);
  int*   cnt  = (int*)  alloc((size_t)N*4);
  int*   rp   = (int*)  alloc((size_t)(N+1)*4);
  int*   bsum = (int*)  alloc(128*4);
  int*   csrc = (int*)  alloc((size_t)E*4);
  uint4* Wp1  = (uint4*)alloc(8192*16);
  uint4* Wp2  = (uint4*)alloc(8192*16);
  float* hp   = (float*)alloc((size_t)64*256*4);
  float* gxb  = (float*)alloc((size_t)64*768*4);
  (void)ws_size; (void)n_in; (void)out_size;

  hipMemsetAsync(cnt, 0, (size_t)N*4, stream);
  hipMemsetAsync(hp,  0, (size_t)64*256*4, stream);

  // CSR build + degree + weight packing
  count_kernel<<<(E+255)/256, 256, 0, stream>>>(ei, cnt, E);
  dis_kernel<<<(N+255)/256, 256, 0, stream>>>(cnt, dis, N);
  int nb = (N + 1023) / 1024;
  scan_block_kernel<<<nb, 1024, 0, stream>>>(cnt, rp, bsum, N);
  scan_sums_kernel<<<1, 128, 0, stream>>>(bsum, nb);
  add_off_kernel<<<(N+255)/256, 256, 0, stream>>>(rp, bsum, cnt, N);
  fill_kernel<<<(E+255)/256, 256, 0, stream>>>(ei, rp, cnt, csrc, E);
  packW_kernel<<<32, 256, 0, stream>>>(W1, Wp1);
  packW_kernel<<<32, 256, 0, stream>>>(W2, Wp2);

  // GCN layer 1
  gemm_mfma<false><<<dim3((N+127)/128, 2), 256, 0, stream>>>(x, Wp1, bufA, N);
  agg_kernel<<<(N+7)/8, 256, 0, stream>>>(bufA, dis, rp, csrc, b1, bufB, N);
  // GCN layer 2
  gemm_mfma<true><<<dim3((N+127)/128, 2), 256, 0, stream>>>(bufB, Wp2, bufA, N);
  agg_kernel<<<(N+7)/8, 256, 0, stream>>>(bufA, dis, rp, csrc, b2, bufB, N);

  // pool + GRU + classifier
  pool_kernel<<<dim3(64, 8), 256, 0, stream>>>(bufB, ptr, hp);
  gx_kernel<<<64, 768, 0, stream>>>(hp, ptr, wih, bih, bhh, gxb);
  gru_kernel<<<1, 512, 0, stream>>>(gxb, whh, bhh, Wc, bc, outp);
}

// Round 5
// 833.365 us; speedup vs baseline: 1.0067x; 1.0027x over previous
//
#include <hip/hip_runtime.h>
#include <hip/hip_bf16.h>
#include <math.h>

// Problem constants (fixed by reference): N=100000 nodes, E=1.6M edges, H=256, T=64.

static inline size_t align512(size_t x){ return (x + 511) & ~size_t(511); }

typedef _Float16 h2_t __attribute__((ext_vector_type(2)));
typedef unsigned short ushort_t;
typedef short bf16x8 __attribute__((ext_vector_type(8)));   // 8 bf16 = 4 VGPRs (MFMA A/B frag)
typedef float f32x4 __attribute__((ext_vector_type(4)));    // MFMA C/D frag
typedef float f32x2 __attribute__((ext_vector_type(2)));

#if defined(__has_builtin)
#if __has_builtin(__builtin_amdgcn_fdot2)
#define HAS_FDOT2 1
#endif
#if __has_builtin(__builtin_amdgcn_cvt_pk_f32_fp8) && __has_builtin(__builtin_amdgcn_cvt_pk_fp8_f32)
#define HAS_FP8CVT 1
#endif
#endif

__device__ inline ushort_t f2bf(float f){
  unsigned u = __float_as_uint(f);
  unsigned r = u + 0x7FFFu + ((u >> 16) & 1u);   // RTNE
  return (ushort_t)(r >> 16);
}
__device__ inline float bf2f(ushort_t h){ return __uint_as_float(((unsigned)h) << 16); }
__device__ inline unsigned pk2bf(float lo, float hi){
  return ((unsigned)f2bf(hi) << 16) | (unsigned)f2bf(lo);
}
__device__ inline bf16x8 as_bf16x8(uint4 u){
  union { uint4 u4; bf16x8 b; } c; c.u4 = u; return c.b;
}

// ---- fp8 e4m3 encode/decode (HW cvt on gfx950; SW fallback approximate) ----

__device__ inline unsigned char f2fp8(float x){
#ifdef HAS_FP8CVT
  int p = __builtin_amdgcn_cvt_pk_fp8_f32(x, x, 0, false);
  return (unsigned char)(p & 0xFF);
#else
  unsigned u = __float_as_uint(x);
  unsigned s = (u >> 24) & 0x80u;
  unsigned um = u & 0x7FFFFFFFu;
  if (um >= 0x43E00000u) return (unsigned char)(s | 0x7E);      // clamp to 448
  if (um <  0x3C000000u) return (unsigned char)s;               // flush < 2^-7
  unsigned r = um + 0x7FFFFu + ((um >> 20) & 1u);               // RTNE at bit 20
  unsigned e = (r >> 23) & 0xFF, m = (r >> 20) & 7u;
  return (unsigned char)(s | ((e - 120u) << 3) | m);
#endif
}
__device__ inline void fp8x4_to_f32(unsigned v, float& a, float& b, float& c, float& d){
#ifdef HAS_FP8CVT
  f32x2 lo = __builtin_amdgcn_cvt_pk_f32_fp8(v, false);
  f32x2 hi = __builtin_amdgcn_cvt_pk_f32_fp8(v, true);
  a = lo.x; b = lo.y; c = hi.x; d = hi.y;
#else
  auto d1 = [](unsigned char t)->float{
    unsigned s = (t >> 7) & 1u, e = (t >> 3) & 0xFu, m = t & 7u;
    float v = (e == 0) ? ldexpf((float)m, -9) : ldexpf(8.0f + (float)m, (int)e - 10);
    return s ? -v : v;
  };
  a = d1(v & 0xFF); b = d1((v >> 8) & 0xFF); c = d1((v >> 16) & 0xFF); d = d1(v >> 24);
#endif
}

// ---------- CSR build ----------

__global__ void count_kernel(const int* __restrict__ ei, int* __restrict__ cnt, int E){
  int e = blockIdx.x*256 + threadIdx.x;
  if (e < E) atomicAdd(&cnt[ei[E + e]], 1);
}

__global__ void dis_kernel(const int* __restrict__ cnt, float* __restrict__ dis, int N){
  int i = blockIdx.x*256 + threadIdx.x;
  if (i < N) dis[i] = rsqrtf((float)cnt[i] + 1.0f);
}

__global__ void scan_block_kernel(const int* __restrict__ cnt, int* __restrict__ rp,
                                  int* __restrict__ bsum, int N){
  __shared__ int s[2][1024];
  int t = threadIdx.x; int i = blockIdx.x*1024 + t;
  int v = (i < N) ? cnt[i] : 0;
  int cur = 0; s[0][t] = v; __syncthreads();
  for (int off = 1; off < 1024; off <<= 1){
    int nxt = cur ^ 1;
    int val = s[cur][t];
    if (t >= off) val += s[cur][t - off];
    s[nxt][t] = val; cur = nxt; __syncthreads();
  }
  if (i < N) rp[i+1] = s[cur][t];
  if (t == 1023) bsum[blockIdx.x] = s[cur][1023];
}

__global__ void scan_sums_kernel(int* __restrict__ bsum, int nb){
  __shared__ int s[128];
  int t = threadIdx.x;
  if (t < nb) s[t] = bsum[t];
  __syncthreads();
  if (t == 0){ int acc = 0; for (int b = 0; b < nb; b++){ int v = s[b]; s[b] = acc; acc += v; } }
  __syncthreads();
  if (t < nb) bsum[t] = s[t];
}

__global__ void add_off_kernel(int* __restrict__ rp, const int* __restrict__ bsum,
                               int* __restrict__ cnt, int N){
  int i = blockIdx.x*256 + threadIdx.x;
  if (i < N){ rp[i+1] += bsum[i >> 10]; cnt[i] = 0; }
  if (i == 0) rp[0] = 0;
}

__global__ void fill_kernel(const int* __restrict__ ei, const int* __restrict__ rp,
                            int* __restrict__ cnt, int* __restrict__ csrc, int E){
  int e = blockIdx.x*256 + threadIdx.x;
  if (e < E){
    int s = ei[e]; int d = ei[E + e];
    int pos = rp[d] + atomicAdd(&cnt[d], 1);
    csrc[pos] = s;
  }
}

// ---------- pack W (256x256 fp32 [k][n]) into MFMA B-fragment order (bf16) ----------

__global__ void packW_kernel(const float* __restrict__ W, uint4* __restrict__ Wp){
  int idx = blockIdx.x*256 + threadIdx.x;    // 0..8191
  int lane = idx & 63;
  int blk  = idx >> 6;                        // 0..127
  int q    = blk & 7;
  int t16  = blk >> 3;                        // 0..15 (16-col group)
  int n = t16*16 + (lane & 15);
  int k = q*32 + (lane >> 4)*8;
  uint4 v;
  v.x = pk2bf(W[(size_t)(k+0)*256 + n], W[(size_t)(k+1)*256 + n]);
  v.y = pk2bf(W[(size_t)(k+2)*256 + n], W[(size_t)(k+3)*256 + n]);
  v.z = pk2bf(W[(size_t)(k+4)*256 + n], W[(size_t)(k+5)*256 + n]);
  v.w = pk2bf(W[(size_t)(k+6)*256 + n], W[(size_t)(k+7)*256 + n]);
  Wp[idx] = v;
}

// ---------- MFMA GEMM: out[N,256](fp8 e4m3) = A[N,256] @ W[256,256] ----------
// 128x128 tile, 4 waves (2x2), each wave 64x64 via 4x4 tiles of 16x16x32 MFMA.
// B register-resident (128 VGPRs). A double-buffered in LDS. Out stored fp8
// (the consumer is the edge-gather, which is fabric-bytes-bound).

template<bool A_BF16>
__global__ __launch_bounds__(256, 2) void gemm_mfma(const void* __restrict__ Ap,
                                                    const uint4* __restrict__ Wp,
                                                    unsigned char* __restrict__ out, int N){
  __shared__ __align__(16) ushort_t As[2][128][40];
  int tid  = threadIdx.x;
  int lane = tid & 63;
  int wave = tid >> 6;
  int wr = wave >> 1, wc = wave & 1;
  int quad = lane >> 4;
  int l15  = lane & 15;
  int r0 = blockIdx.x * 128;
  int cb = blockIdx.y;

  uint4 bfr[4][8];
  {
    const uint4* wpb = Wp + (size_t)(cb*2 + wc) * 2048;
    #pragma unroll
    for (int ct = 0; ct < 4; ct++)
      #pragma unroll
      for (int q = 0; q < 8; q++)
        bfr[ct][q] = wpb[(ct*8 + q)*64 + lane];
  }

  f32x4 acc[4][4];
  #pragma unroll
  for (int rt = 0; rt < 4; rt++)
    #pragma unroll
    for (int ct = 0; ct < 4; ct++)
      acc[rt][ct] = f32x4{0.f, 0.f, 0.f, 0.f};

  int srow = tid >> 1;
  int shalf = tid & 1;
  int grow = min(r0 + srow, N - 1);

  auto load_stage = [&](int it, uint4& v0, uint4& v1){
    int k0 = it*32 + shalf*16;
    if constexpr (A_BF16){
      const ushort_t* Ab = (const ushort_t*)Ap;
      const uint4* ga = (const uint4*)(Ab + (size_t)grow*256 + k0);
      v0 = ga[0]; v1 = ga[1];
    } else {
      const float* Af = (const float*)Ap;
      const float4* ga = (const float4*)(Af + (size_t)grow*256 + k0);
      float4 f0 = ga[0], f1 = ga[1], f2 = ga[2], f3 = ga[3];
      v0.x = pk2bf(f0.x, f0.y); v0.y = pk2bf(f0.z, f0.w);
      v0.z = pk2bf(f1.x, f1.y); v0.w = pk2bf(f1.z, f1.w);
      v1.x = pk2bf(f2.x, f2.y); v1.y = pk2bf(f2.z, f2.w);
      v1.z = pk2bf(f3.x, f3.y); v1.w = pk2bf(f3.z, f3.w);
    }
  };
  auto write_stage = [&](int b, uint4 v0, uint4 v1){
    *(uint4*)&As[b][srow][shalf*16]     = v0;
    *(uint4*)&As[b][srow][shalf*16 + 8] = v1;
  };

  {
    uint4 v0, v1;
    load_stage(0, v0, v1);
    write_stage(0, v0, v1);
  }
  __syncthreads();

  #pragma unroll
  for (int it = 0; it < 8; it++){
    const int b = it & 1;
    uint4 n0, n1;
    if (it < 7) load_stage(it + 1, n0, n1);
    #pragma unroll
    for (int rt = 0; rt < 4; rt++){
      int arow = wr*64 + rt*16 + l15;
      uint4 av = *(const uint4*)&As[b][arow][quad*8];
      bf16x8 af = as_bf16x8(av);
      #pragma unroll
      for (int ct = 0; ct < 4; ct++)
        acc[rt][ct] = __builtin_amdgcn_mfma_f32_16x16x32_bf16(
            af, as_bf16x8(bfr[ct][it]), acc[rt][ct], 0, 0, 0);
    }
    if (it < 7){
      write_stage(b ^ 1, n0, n1);
      __syncthreads();
    }
  }

  // store C (fp8): row = r0+wr*64+rt*16+quad*4+g, col = cb*128+wc*64+ct*16+l15
  int crow0 = r0 + wr*64 + quad*4;
  int ccol0 = cb*128 + wc*64 + l15;
  #pragma unroll
  for (int rt = 0; rt < 4; rt++){
    #pragma unroll
    for (int g = 0; g < 4; g++){
      int row = crow0 + rt*16 + g;
      if (row < N){
        #pragma unroll
        for (int ct = 0; ct < 4; ct++)
          out[(size_t)row*256 + ccol0 + ct*16] = f2fp8(acc[rt][ct][g]);
      }
    }
  }
}

// ---------- GCN aggregation (fp8 gather -> bf16 out): half-wave (32 lanes) per
// node, 8 fp8 cols per lane as one 8B uint2 load (256B/row, fully coalesced).

__global__ __launch_bounds__(256) void agg_kernel(const unsigned char* __restrict__ xw,
                                                  const float* __restrict__ dis,
                                                  const int* __restrict__ rp,
                                                  const int* __restrict__ csrc,
                                                  const float* __restrict__ bias,
                                                  ushort_t* __restrict__ out, int N){
  int node = blockIdx.x*8 + (threadIdx.x >> 5);
  int lane = threadIdx.x & 31;
  if (node >= N) return;
  const uint2* xw2 = (const uint2*)xw;     // 8 B = 8 fp8; row = 32 uint2
  float di = dis[node];
  float sc = di * di;
  float acc[8];
  {
    uint2 a = xw2[(size_t)node*32 + lane];
    float v0,v1,v2,v3,v4,v5,v6,v7;
    fp8x4_to_f32(a.x, v0, v1, v2, v3);
    fp8x4_to_f32(a.y, v4, v5, v6, v7);
    acc[0]=v0*sc; acc[1]=v1*sc; acc[2]=v2*sc; acc[3]=v3*sc;
    acc[4]=v4*sc; acc[5]=v5*sc; acc[6]=v6*sc; acc[7]=v7*sc;
  }
  int e0 = rp[node], e1 = rp[node+1];
  for (int e = e0; e < e1; e++){
    int s = csrc[e];
    float cc = dis[s] * di;
    uint2 v = xw2[(size_t)s*32 + lane];
    float v0,v1,v2,v3,v4,v5,v6,v7;
    fp8x4_to_f32(v.x, v0, v1, v2, v3);
    fp8x4_to_f32(v.y, v4, v5, v6, v7);
    acc[0] = fmaf(v0, cc, acc[0]);
    acc[1] = fmaf(v1, cc, acc[1]);
    acc[2] = fmaf(v2, cc, acc[2]);
    acc[3] = fmaf(v3, cc, acc[3]);
    acc[4] = fmaf(v4, cc, acc[4]);
    acc[5] = fmaf(v5, cc, acc[5]);
    acc[6] = fmaf(v6, cc, acc[6]);
    acc[7] = fmaf(v7, cc, acc[7]);
  }
  const float4* b4 = (const float4*)bias;   // cols lane*8..lane*8+7
  float4 bA = b4[lane*2], bB = b4[lane*2+1];
  acc[0] = fmaxf(acc[0] + bA.x, 0.f);
  acc[1] = fmaxf(acc[1] + bA.y, 0.f);
  acc[2] = fmaxf(acc[2] + bA.z, 0.f);
  acc[3] = fmaxf(acc[3] + bA.w, 0.f);
  acc[4] = fmaxf(acc[4] + bB.x, 0.f);
  acc[5] = fmaxf(acc[5] + bB.y, 0.f);
  acc[6] = fmaxf(acc[6] + bB.z, 0.f);
  acc[7] = fmaxf(acc[7] + bB.w, 0.f);
  uint4 o;
  o.x = pk2bf(acc[0], acc[1]);
  o.y = pk2bf(acc[2], acc[3]);
  o.z = pk2bf(acc[4], acc[5]);
  o.w = pk2bf(acc[6], acc[7]);
  ((uint4*)out)[(size_t)node*32 + lane] = o;
}

// ---------- mean pool (bf16 input, fp32 accumulate) ----------

__global__ void pool_kernel(const ushort_t* __restrict__ h, const int* __restrict__ ptr,
                            float* __restrict__ hp){
  int t = blockIdx.x; int part = blockIdx.y; int c = threadIdx.x;
  int s0 = ptr[t], s1 = ptr[t+1];
  int len = s1 - s0;
  int chunk = (len + 7) / 8;
  int r0 = s0 + part*chunk;
  int r1 = min(r0 + chunk, s1);
  float acc = 0.f;
  for (int r = r0; r < r1; r++) acc += bf2f(h[(size_t)r*256 + c]);
  if (r1 > r0) atomicAdd(&hp[t*256 + c], acc);
}

// ---------- GX[t,g] = dot(hp[t]/cnt[t], w_ih[g]) + b_ih[g] (+ b_hh[g] for r,z
// gates, folded here so the GRU loop carries 2 fewer live VGPRs) ----------

__global__ __launch_bounds__(768) void gx_kernel(const float* __restrict__ hp,
                                                 const int* __restrict__ ptr,
                                                 const float* __restrict__ wih,
                                                 const float* __restrict__ bih,
                                                 const float* __restrict__ bhh,
                                                 float* __restrict__ gx){
  __shared__ float xs[256];
  int t = blockIdx.x; int g = threadIdx.x;
  if (g < 256){
    float cf = (float)max(ptr[t+1] - ptr[t], 1);
    xs[g] = hp[t*256 + g] / cf;
  }
  __syncthreads();
  float acc = bih[g] + (g < 512 ? bhh[g] : 0.f);
  const float* wr = wih + (size_t)g*256;
  #pragma unroll 4
  for (int k = 0; k < 256; k++) acc = fmaf(xs[k], wr[k], acc);
  gx[t*768 + g] = acc;
}

// ---------- sequential GRU: single block, 512 threads (2 threads/gate).
// REGISTER MATH (the lesson of rounds 0-4): wr[64]+wz[64]+wn[64] of h2_t
// (4B each) = 192 VGPRs/thread of weights. Under a 128-VGPR cap this can
// NEVER be resident -> rounds 0/4 spilled (16KB..344KB scratch) and
// re-streamed from L2 every step (~2.2us/step).
// Launch-bounds 2nd arg is BLOCKS/CU (CUDA semantics, verified r0/r1:
// (512,2)->128 VGPR cap, (1024,4)->64 cap). So (512,1): 8 waves/CU =
// 2 waves/SIMD -> 256-VGPR cap. Demand ~222 < 256 -> full W_hh truly
// register-resident, zero spill. The GRU is one block on the whole
// device; occupancy beyond its own waves is irrelevant.
// Also: ONE barrier/step (double-buffered hh), next-step gx prefetch,
// native exp/rcp transcendentals, r/z biases folded into gx.

__device__ inline float fast_sig(float x){
  return __builtin_amdgcn_rcpf(1.f + __expf(-x));
}
__device__ inline float fast_tanh(float x){
  // 1 - 2/(e^{2x}+1); exact limits at +-inf via rcp(inf)=0
  return 1.f - 2.f*__builtin_amdgcn_rcpf(1.f + __expf(2.f*x));
}

__global__ __launch_bounds__(512, 1) void gru_kernel(const float* __restrict__ gx,
                                                     const float* __restrict__ whh,
                                                     const float* __restrict__ bhh,
                                                     const float* __restrict__ Wc,
                                                     const float* __restrict__ bc,
                                                     float* __restrict__ out){
  __shared__ __align__(16) _Float16 hh[2][256];
  __shared__ float hfin[256];
  int tid = threadIdx.x;
  int i = tid >> 1;        // gate index 0..255
  int half = tid & 1;      // k-half (128 floats = 64 h2)

  h2_t wr[64], wz[64], wn[64];
  {
    const float2* w2 = (const float2*)whh;
    size_t base = (size_t)half * 64;
    const float2* pr = w2 + (size_t)i*128       + base;
    const float2* pz = w2 + (size_t)(i+256)*128 + base;
    const float2* pn = w2 + (size_t)(i+512)*128 + base;
    #pragma unroll
    for (int k = 0; k < 64; k++){
      float2 a = pr[k];
      float2 b = pz[k];
      float2 c = pn[k];
      wr[k] = h2_t{(_Float16)a.x, (_Float16)a.y};
      wz[k] = h2_t{(_Float16)b.x, (_Float16)b.y};
      wn[k] = h2_t{(_Float16)c.x, (_Float16)c.y};
    }
  }
  float bN = bhh[i + 512];           // r,z biases folded into gx upstream
  if (tid < 256) hh[0][tid] = (_Float16)0.f;
  float h = 0.f;
  // prefetch t=0 gx
  float gxr = gx[i], gxz = gx[256 + i], gxn = gx[512 + i];
  __syncthreads();

  for (int t = 0; t < 64; t++){
    // prefetch next step's gx; consumed after this step's compute
    float ngr = 0.f, ngz = 0.f, ngn = 0.f;
    if (t < 63){
      const float* g = gx + (size_t)(t+1)*768;
      ngr = g[i]; ngz = g[256 + i]; ngn = g[512 + i];
    }
    const h2_t* hp2 = ((const h2_t*)hh[t & 1]) + half*64;
    float aR0=0.f, aR1=0.f, aZ0=0.f, aZ1=0.f, aN0=0.f, aN1=0.f;
    #pragma unroll
    for (int k = 0; k < 64; k += 2){
      h2_t h0 = hp2[k];
      h2_t h1 = hp2[k+1];
#ifdef HAS_FDOT2
      aR0 = __builtin_amdgcn_fdot2(h0, wr[k],   aR0, false);
      aZ0 = __builtin_amdgcn_fdot2(h0, wz[k],   aZ0, false);
      aN0 = __builtin_amdgcn_fdot2(h0, wn[k],   aN0, false);
      aR1 = __builtin_amdgcn_fdot2(h1, wr[k+1], aR1, false);
      aZ1 = __builtin_amdgcn_fdot2(h1, wz[k+1], aZ1, false);
      aN1 = __builtin_amdgcn_fdot2(h1, wn[k+1], aN1, false);
#else
      aR0 = fmaf((float)h0.x, (float)wr[k].x, aR0);
      aR0 = fmaf((float)h0.y, (float)wr[k].y, aR0);
      aZ0 = fmaf((float)h0.x, (float)wz[k].x, aZ0);
      aZ0 = fmaf((float)h0.y, (float)wz[k].y, aZ0);
      aN0 = fmaf((float)h0.x, (float)wn[k].x, aN0);
      aN0 = fmaf((float)h0.y, (float)wn[k].y, aN0);
      aR1 = fmaf((float)h1.x, (float)wr[k+1].x, aR1);
      aR1 = fmaf((float)h1.y, (float)wr[k+1].y, aR1);
      aZ1 = fmaf((float)h1.x, (float)wz[k+1].x, aZ1);
      aZ1 = fmaf((float)h1.y, (float)wz[k+1].y, aZ1);
      aN1 = fmaf((float)h1.x, (float)wn[k+1].x, aN1);
      aN1 = fmaf((float)h1.y, (float)wn[k+1].y, aN1);
#endif
    }
    float accR = aR0 + aR1, accZ = aZ0 + aZ1, accN = aN0 + aN1;
    accR += __shfl_xor(accR, 1);
    accZ += __shfl_xor(accZ, 1);
    accN += __shfl_xor(accN, 1);
    float r = fast_sig(gxr + accR);
    float z = fast_sig(gxz + accZ);
    float n = fast_tanh(gxn + r*(accN + bN));
    float hnew = (1.f - z)*n + z*h;
    if (half == 0) hh[(t & 1) ^ 1][i] = (_Float16)hnew;
    gxr = ngr; gxz = ngz; gxn = ngn;
    h = hnew;
    __syncthreads();
  }

  if (half == 0) hfin[i] = h;
  __syncthreads();
  if (tid < 64){
    int r = tid >> 2, qq = tid & 3;
    const float4* wrow = (const float4*)(Wc + (size_t)r*256 + (size_t)qq*64);
    const float4* hv = (const float4*)(hfin + (size_t)qq*64);
    float acc = 0.f;
    #pragma unroll
    for (int k = 0; k < 16; k++){
      float4 wv = wrow[k];
      float4 xv = hv[k];
      acc = fmaf(wv.x, xv.x, acc);
      acc = fmaf(wv.y, xv.y, acc);
      acc = fmaf(wv.z, xv.z, acc);
      acc = fmaf(wv.w, xv.w, acc);
    }
    acc += __shfl_xor(acc, 1);
    acc += __shfl_xor(acc, 2);
    if (qq == 0) out[r] = acc + bc[r];
  }
}

extern "C" void kernel_launch(void* const* d_in, const int* in_sizes, int n_in,
                              void* d_out, int out_size, void* d_ws, size_t ws_size,
                              hipStream_t stream){
  const float* x   = (const float*)d_in[0];
  const int*   ei  = (const int*)d_in[1];
  const int*   ptr = (const int*)d_in[2];
  const float* W1  = (const float*)d_in[3];
  const float* b1  = (const float*)d_in[4];
  const float* W2  = (const float*)d_in[5];
  const float* b2  = (const float*)d_in[6];
  const float* wih = (const float*)d_in[7];
  const float* whh = (const float*)d_in[8];
  const float* bih = (const float*)d_in[9];
  const float* bhh = (const float*)d_in[10];
  const float* Wc  = (const float*)d_in[11];
  const float* bc  = (const float*)d_in[12];
  float* outp = (float*)d_out;

  const int N = in_sizes[0] / 256;   // 100000
  const int E = in_sizes[1] / 2;     // 1600000

  char* w = (char*)d_ws;
  size_t off = 0;
  auto alloc = [&](size_t bytes){ void* p = w + off; off = align512(off + bytes); return p; };
  unsigned char* bufA = (unsigned char*)alloc((size_t)N*256);     // xw (fp8 e4m3)
  ushort_t*      bufB = (ushort_t*)alloc((size_t)N*256*2);        // h  (bf16)
  float* dis  = (float*)alloc((size_t)N*4);
  int*   cnt  = (int*)  alloc((size_t)N*4);
  int*   rp   = (int*)  alloc((size_t)(N+1)*4);
  int*   bsum = (int*)  alloc(128*4);
  int*   csrc = (int*)  alloc((size_t)E*4);
  uint4* Wp1  = (uint4*)alloc(8192*16);
  uint4* Wp2  = (uint4*)alloc(8192*16);
  float* hp   = (float*)alloc((size_t)64*256*4);
  float* gxb  = (float*)alloc((size_t)64*768*4);
  (void)ws_size; (void)n_in; (void)out_size;

  hipMemsetAsync(cnt, 0, (size_t)N*4, stream);
  hipMemsetAsync(hp,  0, (size_t)64*256*4, stream);

  // CSR build + degree + weight packing
  count_kernel<<<(E+255)/256, 256, 0, stream>>>(ei, cnt, E);
  dis_kernel<<<(N+255)/256, 256, 0, stream>>>(cnt, dis, N);
  int nb = (N + 1023) / 1024;
  scan_block_kernel<<<nb, 1024, 0, stream>>>(cnt, rp, bsum, N);
  scan_sums_kernel<<<1, 128, 0, stream>>>(bsum, nb);
  add_off_kernel<<<(N+255)/256, 256, 0, stream>>>(rp, bsum, cnt, N);
  fill_kernel<<<(E+255)/256, 256, 0, stream>>>(ei, rp, cnt, csrc, E);
  packW_kernel<<<32, 256, 0, stream>>>(W1, Wp1);
  packW_kernel<<<32, 256, 0, stream>>>(W2, Wp2);

  // GCN layer 1
  gemm_mfma<false><<<dim3((N+127)/128, 2), 256, 0, stream>>>(x, Wp1, bufA, N);
  agg_kernel<<<(N+7)/8, 256, 0, stream>>>(bufA, dis, rp, csrc, b1, bufB, N);
  // GCN layer 2
  gemm_mfma<true><<<dim3((N+127)/128, 2), 256, 0, stream>>>(bufB, Wp2, bufA, N);
  agg_kernel<<<(N+7)/8, 256, 0, stream>>>(bufA, dis, rp, csrc, b2, bufB, N);

  // pool + GRU + classifier
  pool_kernel<<<dim3(64, 8), 256, 0, stream>>>(bufB, ptr, hp);
  gx_kernel<<<64, 768, 0, stream>>>(hp, ptr, wih, bih, bhh, gxb);
  gru_kernel<<<1, 512, 0, stream>>>(gxb, whh, bhh, Wc, bc, outp);
}

// Round 6
// 784.921 us; speedup vs baseline: 1.0688x; 1.0617x over previous
//
#include <hip/hip_runtime.h>
#include <hip/hip_bf16.h>
#include <math.h>

// Problem constants (fixed by reference): N=100000 nodes, E=1.6M edges, H=256, T=64.

static inline size_t align512(size_t x){ return (x + 511) & ~size_t(511); }

typedef _Float16 h2_t __attribute__((ext_vector_type(2)));
typedef unsigned short ushort_t;
typedef short bf16x8 __attribute__((ext_vector_type(8)));   // 8 bf16 = 4 VGPRs (MFMA A/B frag)
typedef float f32x4 __attribute__((ext_vector_type(4)));    // MFMA C/D frag
typedef float f32x2 __attribute__((ext_vector_type(2)));

#if defined(__has_builtin)
#if __has_builtin(__builtin_amdgcn_fdot2)
#define HAS_FDOT2 1
#endif
#if __has_builtin(__builtin_amdgcn_cvt_pk_f32_fp8) && __has_builtin(__builtin_amdgcn_cvt_pk_fp8_f32)
#define HAS_FP8CVT 1
#endif
#endif

__device__ inline ushort_t f2bf(float f){
  unsigned u = __float_as_uint(f);
  unsigned r = u + 0x7FFFu + ((u >> 16) & 1u);   // RTNE
  return (ushort_t)(r >> 16);
}
__device__ inline float bf2f(ushort_t h){ return __uint_as_float(((unsigned)h) << 16); }
__device__ inline unsigned pk2bf(float lo, float hi){
  return ((unsigned)f2bf(hi) << 16) | (unsigned)f2bf(lo);
}
__device__ inline bf16x8 as_bf16x8(uint4 u){
  union { uint4 u4; bf16x8 b; } c; c.u4 = u; return c.b;
}
__device__ inline h2_t u2h2(unsigned u){
  union { unsigned u; h2_t h; } c; c.u = u; return c.h;
}
__device__ inline float fdot2a(h2_t a, h2_t b, float c){
#ifdef HAS_FDOT2
  return __builtin_amdgcn_fdot2(a, b, c, false);
#else
  return fmaf((float)a.x, (float)b.x, fmaf((float)a.y, (float)b.y, c));
#endif
}

// ---- fp8 e4m3 encode/decode (HW cvt on gfx950; SW fallback approximate) ----

__device__ inline unsigned char f2fp8(float x){
#ifdef HAS_FP8CVT
  int p = __builtin_amdgcn_cvt_pk_fp8_f32(x, x, 0, false);
  return (unsigned char)(p & 0xFF);
#else
  unsigned u = __float_as_uint(x);
  unsigned s = (u >> 24) & 0x80u;
  unsigned um = u & 0x7FFFFFFFu;
  if (um >= 0x43E00000u) return (unsigned char)(s | 0x7E);      // clamp to 448
  if (um <  0x3C000000u) return (unsigned char)s;               // flush < 2^-7
  unsigned r = um + 0x7FFFFu + ((um >> 20) & 1u);               // RTNE at bit 20
  unsigned e = (r >> 23) & 0xFF, m = (r >> 20) & 7u;
  return (unsigned char)(s | ((e - 120u) << 3) | m);
#endif
}
__device__ inline void fp8x4_to_f32(unsigned v, float& a, float& b, float& c, float& d){
#ifdef HAS_FP8CVT
  f32x2 lo = __builtin_amdgcn_cvt_pk_f32_fp8(v, false);
  f32x2 hi = __builtin_amdgcn_cvt_pk_f32_fp8(v, true);
  a = lo.x; b = lo.y; c = hi.x; d = hi.y;
#else
  auto d1 = [](unsigned char t)->float{
    unsigned s = (t >> 7) & 1u, e = (t >> 3) & 0xFu, m = t & 7u;
    float v = (e == 0) ? ldexpf((float)m, -9) : ldexpf(8.0f + (float)m, (int)e - 10);
    return s ? -v : v;
  };
  a = d1(v & 0xFF); b = d1((v >> 8) & 0xFF); c = d1((v >> 16) & 0xFF); d = d1(v >> 24);
#endif
}

// ---------- CSR build ----------

__global__ void count_kernel(const int* __restrict__ ei, int* __restrict__ cnt, int E){
  int e = blockIdx.x*256 + threadIdx.x;
  if (e < E) atomicAdd(&cnt[ei[E + e]], 1);
}

__global__ void dis_kernel(const int* __restrict__ cnt, float* __restrict__ dis, int N){
  int i = blockIdx.x*256 + threadIdx.x;
  if (i < N) dis[i] = rsqrtf((float)cnt[i] + 1.0f);
}

__global__ void scan_block_kernel(const int* __restrict__ cnt, int* __restrict__ rp,
                                  int* __restrict__ bsum, int N){
  __shared__ int s[2][1024];
  int t = threadIdx.x; int i = blockIdx.x*1024 + t;
  int v = (i < N) ? cnt[i] : 0;
  int cur = 0; s[0][t] = v; __syncthreads();
  for (int off = 1; off < 1024; off <<= 1){
    int nxt = cur ^ 1;
    int val = s[cur][t];
    if (t >= off) val += s[cur][t - off];
    s[nxt][t] = val; cur = nxt; __syncthreads();
  }
  if (i < N) rp[i+1] = s[cur][t];
  if (t == 1023) bsum[blockIdx.x] = s[cur][1023];
}

__global__ void scan_sums_kernel(int* __restrict__ bsum, int nb){
  __shared__ int s[128];
  int t = threadIdx.x;
  if (t < nb) s[t] = bsum[t];
  __syncthreads();
  if (t == 0){ int acc = 0; for (int b = 0; b < nb; b++){ int v = s[b]; s[b] = acc; acc += v; } }
  __syncthreads();
  if (t < nb) bsum[t] = s[t];
}

__global__ void add_off_kernel(int* __restrict__ rp, const int* __restrict__ bsum,
                               int* __restrict__ cnt, int N){
  int i = blockIdx.x*256 + threadIdx.x;
  if (i < N){ rp[i+1] += bsum[i >> 10]; cnt[i] = 0; }
  if (i == 0) rp[0] = 0;
}

__global__ void fill_kernel(const int* __restrict__ ei, const int* __restrict__ rp,
                            int* __restrict__ cnt, int* __restrict__ csrc, int E){
  int e = blockIdx.x*256 + threadIdx.x;
  if (e < E){
    int s = ei[e]; int d = ei[E + e];
    int pos = rp[d] + atomicAdd(&cnt[d], 1);
    csrc[pos] = s;
  }
}

// ---------- pack W (256x256 fp32 [k][n]) into MFMA B-fragment order (bf16) ----------

__global__ void packW_kernel(const float* __restrict__ W, uint4* __restrict__ Wp){
  int idx = blockIdx.x*256 + threadIdx.x;    // 0..8191
  int lane = idx & 63;
  int blk  = idx >> 6;                        // 0..127
  int q    = blk & 7;
  int t16  = blk >> 3;                        // 0..15 (16-col group)
  int n = t16*16 + (lane & 15);
  int k = q*32 + (lane >> 4)*8;
  uint4 v;
  v.x = pk2bf(W[(size_t)(k+0)*256 + n], W[(size_t)(k+1)*256 + n]);
  v.y = pk2bf(W[(size_t)(k+2)*256 + n], W[(size_t)(k+3)*256 + n]);
  v.z = pk2bf(W[(size_t)(k+4)*256 + n], W[(size_t)(k+5)*256 + n]);
  v.w = pk2bf(W[(size_t)(k+6)*256 + n], W[(size_t)(k+7)*256 + n]);
  Wp[idx] = v;
}

// ---------- pack W_hh (768x256 f32) into 3-tier GRU layout (f16 h2 units) ----
// Thread t=(i,half) of the 512-thread GRU owns, per gate g in {r,z,n}, the 64
// h2 values hk = half*64 + c*8 + j (c=chunk 0..7, j=0..7) of row i+g*256.
// Tiers (per thread): REG 88 h2 = r(all 64) + z(c0..2);  LDS 72 h2 =
// z(c3..7)=40 + n(c0..3)=32;  STREAM 32 h2 = n(c4..7), replicated x2 so the
// per-step reload address alternates with t&1 (blocks LICM reg-hoisting).
// Layouts (unsigned=1 h2):  REG:  [22][512] uint4, slot s -> word s>>2, comp s&3
//                           LDS:  [36][512] uint2, item li -> pair li>>1, comp li&1
//                           STRM: [2][8][512] uint4, item si -> grp si>>2, comp si&3
#define WHHP_LBASE 45056u
#define WHHP_SBASE 81920u
#define WHHP_SREP  16384u
#define WHHP_TOTAL 114688u

__global__ void packWhh_kernel(const float* __restrict__ whh, unsigned* __restrict__ wp){
  int idx = blockIdx.x*256 + threadIdx.x;        // 0..98303
  if (idx >= 98304) return;
  int t = idx / 192;
  int m = idx - t*192;
  int i = t >> 1, half = t & 1;
  int g  = m >> 6;            // 0=r,1=z,2=n
  int mg = m & 63;
  int c = mg >> 3, j = mg & 7;
  int hk = half*64 + c*8 + j;
  int row = i + g*256;
  float a = whh[(size_t)row*256 + 2*hk];
  float b = whh[(size_t)row*256 + 2*hk + 1];
  union { _Float16 f[2]; unsigned u; } cv;
  cv.f[0] = (_Float16)a; cv.f[1] = (_Float16)b;
  if (g == 0){
    int s = c*8 + j;
    wp[(unsigned)((s >> 2)*2048 + t*4 + (s & 3))] = cv.u;
  } else if (g == 1 && c < 3){
    int s = 64 + c*8 + j;
    wp[(unsigned)((s >> 2)*2048 + t*4 + (s & 3))] = cv.u;
  } else if (g == 1){
    int li = (c-3)*8 + j;
    wp[WHHP_LBASE + (unsigned)((li >> 1)*1024 + t*2 + (li & 1))] = cv.u;
  } else if (c < 4){
    int li = 40 + c*8 + j;
    wp[WHHP_LBASE + (unsigned)((li >> 1)*1024 + t*2 + (li & 1))] = cv.u;
  } else {
    int si = (c-4)*8 + j;
    unsigned so = (unsigned)((si >> 2)*2048 + t*4 + (si & 3));
    wp[WHHP_SBASE + so] = cv.u;
    wp[WHHP_SBASE + WHHP_SREP + so] = cv.u;
  }
}

// ---------- MFMA GEMM: out[N,256](fp8 e4m3) = A[N,256] @ W[256,256] ----------
// 128x128 tile, 4 waves (2x2), each wave 64x64 via 4x4 tiles of 16x16x32 MFMA.
// B register-resident (128 VGPRs). A double-buffered in LDS. Out stored fp8
// (the consumer is the edge-gather, which is fabric-bytes-bound).

template<bool A_BF16>
__global__ __launch_bounds__(256, 2) void gemm_mfma(const void* __restrict__ Ap,
                                                    const uint4* __restrict__ Wp,
                                                    unsigned char* __restrict__ out, int N){
  __shared__ __align__(16) ushort_t As[2][128][40];
  int tid  = threadIdx.x;
  int lane = tid & 63;
  int wave = tid >> 6;
  int wr = wave >> 1, wc = wave & 1;
  int quad = lane >> 4;
  int l15  = lane & 15;
  int r0 = blockIdx.x * 128;
  int cb = blockIdx.y;

  uint4 bfr[4][8];
  {
    const uint4* wpb = Wp + (size_t)(cb*2 + wc) * 2048;
    #pragma unroll
    for (int ct = 0; ct < 4; ct++)
      #pragma unroll
      for (int q = 0; q < 8; q++)
        bfr[ct][q] = wpb[(ct*8 + q)*64 + lane];
  }

  f32x4 acc[4][4];
  #pragma unroll
  for (int rt = 0; rt < 4; rt++)
    #pragma unroll
    for (int ct = 0; ct < 4; ct++)
      acc[rt][ct] = f32x4{0.f, 0.f, 0.f, 0.f};

  int srow = tid >> 1;
  int shalf = tid & 1;
  int grow = min(r0 + srow, N - 1);

  auto load_stage = [&](int it, uint4& v0, uint4& v1){
    int k0 = it*32 + shalf*16;
    if constexpr (A_BF16){
      const ushort_t* Ab = (const ushort_t*)Ap;
      const uint4* ga = (const uint4*)(Ab + (size_t)grow*256 + k0);
      v0 = ga[0]; v1 = ga[1];
    } else {
      const float* Af = (const float*)Ap;
      const float4* ga = (const float4*)(Af + (size_t)grow*256 + k0);
      float4 f0 = ga[0], f1 = ga[1], f2 = ga[2], f3 = ga[3];
      v0.x = pk2bf(f0.x, f0.y); v0.y = pk2bf(f0.z, f0.w);
      v0.z = pk2bf(f1.x, f1.y); v0.w = pk2bf(f1.z, f1.w);
      v1.x = pk2bf(f2.x, f2.y); v1.y = pk2bf(f2.z, f2.w);
      v1.z = pk2bf(f3.x, f3.y); v1.w = pk2bf(f3.z, f3.w);
    }
  };
  auto write_stage = [&](int b, uint4 v0, uint4 v1){
    *(uint4*)&As[b][srow][shalf*16]     = v0;
    *(uint4*)&As[b][srow][shalf*16 + 8] = v1;
  };

  {
    uint4 v0, v1;
    load_stage(0, v0, v1);
    write_stage(0, v0, v1);
  }
  __syncthreads();

  #pragma unroll
  for (int it = 0; it < 8; it++){
    const int b = it & 1;
    uint4 n0, n1;
    if (it < 7) load_stage(it + 1, n0, n1);
    #pragma unroll
    for (int rt = 0; rt < 4; rt++){
      int arow = wr*64 + rt*16 + l15;
      uint4 av = *(const uint4*)&As[b][arow][quad*8];
      bf16x8 af = as_bf16x8(av);
      #pragma unroll
      for (int ct = 0; ct < 4; ct++)
        acc[rt][ct] = __builtin_amdgcn_mfma_f32_16x16x32_bf16(
            af, as_bf16x8(bfr[ct][it]), acc[rt][ct], 0, 0, 0);
    }
    if (it < 7){
      write_stage(b ^ 1, n0, n1);
      __syncthreads();
    }
  }

  // store C (fp8): row = r0+wr*64+rt*16+quad*4+g, col = cb*128+wc*64+ct*16+l15
  int crow0 = r0 + wr*64 + quad*4;
  int ccol0 = cb*128 + wc*64 + l15;
  #pragma unroll
  for (int rt = 0; rt < 4; rt++){
    #pragma unroll
    for (int g = 0; g < 4; g++){
      int row = crow0 + rt*16 + g;
      if (row < N){
        #pragma unroll
        for (int ct = 0; ct < 4; ct++)
          out[(size_t)row*256 + ccol0 + ct*16] = f2fp8(acc[rt][ct][g]);
      }
    }
  }
}

// ---------- GCN aggregation (fp8 gather -> bf16 out): half-wave (32 lanes) per
// node, 8 fp8 cols per lane as one 8B uint2 load (256B/row, fully coalesced).

__global__ __launch_bounds__(256) void agg_kernel(const unsigned char* __restrict__ xw,
                                                  const float* __restrict__ dis,
                                                  const int* __restrict__ rp,
                                                  const int* __restrict__ csrc,
                                                  const float* __restrict__ bias,
                                                  ushort_t* __restrict__ out, int N){
  int node = blockIdx.x*8 + (threadIdx.x >> 5);
  int lane = threadIdx.x & 31;
  if (node >= N) return;
  const uint2* xw2 = (const uint2*)xw;     // 8 B = 8 fp8; row = 32 uint2
  float di = dis[node];
  float sc = di * di;
  float acc[8];
  {
    uint2 a = xw2[(size_t)node*32 + lane];
    float v0,v1,v2,v3,v4,v5,v6,v7;
    fp8x4_to_f32(a.x, v0, v1, v2, v3);
    fp8x4_to_f32(a.y, v4, v5, v6, v7);
    acc[0]=v0*sc; acc[1]=v1*sc; acc[2]=v2*sc; acc[3]=v3*sc;
    acc[4]=v4*sc; acc[5]=v5*sc; acc[6]=v6*sc; acc[7]=v7*sc;
  }
  int e0 = rp[node], e1 = rp[node+1];
  for (int e = e0; e < e1; e++){
    int s = csrc[e];
    float cc = dis[s] * di;
    uint2 v = xw2[(size_t)s*32 + lane];
    float v0,v1,v2,v3,v4,v5,v6,v7;
    fp8x4_to_f32(v.x, v0, v1, v2, v3);
    fp8x4_to_f32(v.y, v4, v5, v6, v7);
    acc[0] = fmaf(v0, cc, acc[0]);
    acc[1] = fmaf(v1, cc, acc[1]);
    acc[2] = fmaf(v2, cc, acc[2]);
    acc[3] = fmaf(v3, cc, acc[3]);
    acc[4] = fmaf(v4, cc, acc[4]);
    acc[5] = fmaf(v5, cc, acc[5]);
    acc[6] = fmaf(v6, cc, acc[6]);
    acc[7] = fmaf(v7, cc, acc[7]);
  }
  const float4* b4 = (const float4*)bias;   // cols lane*8..lane*8+7
  float4 bA = b4[lane*2], bB = b4[lane*2+1];
  acc[0] = fmaxf(acc[0] + bA.x, 0.f);
  acc[1] = fmaxf(acc[1] + bA.y, 0.f);
  acc[2] = fmaxf(acc[2] + bA.z, 0.f);
  acc[3] = fmaxf(acc[3] + bA.w, 0.f);
  acc[4] = fmaxf(acc[4] + bB.x, 0.f);
  acc[5] = fmaxf(acc[5] + bB.y, 0.f);
  acc[6] = fmaxf(acc[6] + bB.z, 0.f);
  acc[7] = fmaxf(acc[7] + bB.w, 0.f);
  uint4 o;
  o.x = pk2bf(acc[0], acc[1]);
  o.y = pk2bf(acc[2], acc[3]);
  o.z = pk2bf(acc[4], acc[5]);
  o.w = pk2bf(acc[6], acc[7]);
  ((uint4*)out)[(size_t)node*32 + lane] = o;
}

// ---------- mean pool (bf16 input, fp32 accumulate) ----------

__global__ void pool_kernel(const ushort_t* __restrict__ h, const int* __restrict__ ptr,
                            float* __restrict__ hp){
  int t = blockIdx.x; int part = blockIdx.y; int c = threadIdx.x;
  int s0 = ptr[t], s1 = ptr[t+1];
  int len = s1 - s0;
  int chunk = (len + 7) / 8;
  int r0 = s0 + part*chunk;
  int r1 = min(r0 + chunk, s1);
  float acc = 0.f;
  for (int r = r0; r < r1; r++) acc += bf2f(h[(size_t)r*256 + c]);
  if (r1 > r0) atomicAdd(&hp[t*256 + c], acc);
}

// ---------- GX[t,g] = dot(hp[t]/cnt[t], w_ih[g]) + b_ih[g] (+ b_hh[g] for r,z
// gates, folded here so the GRU loop carries 2 fewer live VGPRs) ----------

__global__ __launch_bounds__(768) void gx_kernel(const float* __restrict__ hp,
                                                 const int* __restrict__ ptr,
                                                 const float* __restrict__ wih,
                                                 const float* __restrict__ bih,
                                                 const float* __restrict__ bhh,
                                                 float* __restrict__ gx){
  __shared__ float xs[256];
  int t = blockIdx.x; int g = threadIdx.x;
  if (g < 256){
    float cf = (float)max(ptr[t+1] - ptr[t], 1);
    xs[g] = hp[t*256 + g] / cf;
  }
  __syncthreads();
  float acc = bih[g] + (g < 512 ? bhh[g] : 0.f);
  const float* wr = wih + (size_t)g*256;
  #pragma unroll 4
  for (int k = 0; k < 256; k++) acc = fmaf(xs[k], wr[k], acc);
  gx[t*768 + g] = acc;
}

// ---------- sequential GRU: single block, 512 threads (2 threads/gate).
// The toolchain caps this kernel at 128 VGPRs no matter what (measured across
// (512,2)/(512,1)/(1024,4)/waves_per_eu: cap == 65536/threads, i.e. the RA
// budgets half the CU register file). Full f16 W_hh = 98304 regs can NEVER be
// register-resident. So: 3-tier residency.
//   REGS  88 h2/thread (180 KB)  - r gate (all) + z chunks 0..2
//   LDS   72 h2/thread (147 KB)  - z chunks 3..7 + n chunks 0..3 (one block
//          on one CU -> entire 160 KB LDS available; h reads are wave-uniform
//          broadcasts so only weight reads pay LDS bandwidth)
//   L2    32 h2/thread (64 KB)   - n chunks 4..7, re-streamed each step with
//          staggered uint4 prefetch; x2-replicated buffer + t&1 base alternation
//          + "#pragma unroll 1" keep LICM from hoisting the loads into regs.
// Per step: ~1150cy LDS weight reads || ~1100cy VALU (192 fdot2) || stream.

__device__ inline float fast_sig(float x){
  return __builtin_amdgcn_rcpf(1.f + __expf(-x));
}
__device__ inline float fast_tanh(float x){
  // 1 - 2/(e^{2x}+1); exact limits at +-inf via rcp(inf)=0
  return 1.f - 2.f*__builtin_amdgcn_rcpf(1.f + __expf(2.f*x));
}

__global__ __launch_bounds__(512, 1) void gru_kernel(const float* __restrict__ gx,
                                                     const unsigned* __restrict__ whhp,
                                                     const float* __restrict__ bhh,
                                                     const float* __restrict__ Wc,
                                                     const float* __restrict__ bc,
                                                     float* __restrict__ out){
  __shared__ uint2 lw2[36*512];                  // 147456 B weight tier
  __shared__ __align__(16) _Float16 hh[2][256];  // 1 KB, double-buffered h
  __shared__ float hfin[256];                    // 1 KB
  int tid = threadIdx.x;
  int i = tid >> 1;        // gate index 0..255
  int half = tid & 1;      // k-half

  // register tier: 22 coalesced uint4 loads
  uint4 wreg4[22];
  {
    const uint4* R4 = (const uint4*)whhp;
    #pragma unroll
    for (int j = 0; j < 22; j++) wreg4[j] = R4[j*512 + tid];
  }
  // LDS tier: cooperative linear copy
  {
    const uint2* Lz2 = (const uint2*)(whhp + WHHP_LBASE);
    #pragma unroll
    for (int r = 0; r < 36; r++) lw2[r*512 + tid] = Lz2[r*512 + tid];
  }

  float bN = bhh[i + 512];           // r,z biases folded into gx upstream
  if (tid < 256) hh[0][tid] = (_Float16)0.f;
  float h = 0.f;
  __syncthreads();

  #pragma unroll 1
  for (int t = 0; t < 64; t++){
    const float* gxt = gx + (size_t)t*768;
    float gxr = gxt[i], gxz = gxt[256 + i], gxn = gxt[512 + i];
    const uint4* hh4 = (const uint4*)((const char*)hh + ((t & 1) << 9) + (half << 8));
    const uint4* S4 = (const uint4*)(whhp + WHHP_SBASE + ((unsigned)(t & 1))*WHHP_SREP);
    // staggered stream prefetch (peak 4 groups = 16 VGPRs in flight)
    uint4 s0 = S4[0*512 + tid], s1 = S4[1*512 + tid];
    uint4 s2, s3, s4, s5, s6, s7;
    float aR0=0.f, aR1=0.f, aZ0=0.f, aZ1=0.f, aN0=0.f, aN1=0.f;
    #pragma unroll
    for (int c = 0; c < 8; c++){
      if (c == 2){ s2 = S4[2*512 + tid]; s3 = S4[3*512 + tid]; }
      if (c == 4){ s4 = S4[4*512 + tid]; s5 = S4[5*512 + tid]; }
      if (c == 5){ s6 = S4[6*512 + tid]; s7 = S4[7*512 + tid]; }
      uint4 hA = hh4[c*2], hB = hh4[c*2 + 1];
      h2_t h0=u2h2(hA.x), h1=u2h2(hA.y), h2v=u2h2(hA.z), h3=u2h2(hA.w);
      h2_t h4=u2h2(hB.x), h5=u2h2(hB.y), h6v=u2h2(hB.z), h7=u2h2(hB.w);
      // ---- r gate: regs words 2c, 2c+1 ----
      {
        uint4 wa = wreg4[c*2], wb = wreg4[c*2 + 1];
        aR0 = fdot2a(h0,  u2h2(wa.x), aR0); aR1 = fdot2a(h1, u2h2(wa.y), aR1);
        aR0 = fdot2a(h2v, u2h2(wa.z), aR0); aR1 = fdot2a(h3, u2h2(wa.w), aR1);
        aR0 = fdot2a(h4,  u2h2(wb.x), aR0); aR1 = fdot2a(h5, u2h2(wb.y), aR1);
        aR0 = fdot2a(h6v, u2h2(wb.z), aR0); aR1 = fdot2a(h7, u2h2(wb.w), aR1);
      }
      // ---- z gate: chunks 0..2 regs (words 16+2c,17+2c), 3..7 LDS pairs ----
      if (c < 3){
        uint4 za = wreg4[16 + c*2], zb = wreg4[17 + c*2];
        aZ0 = fdot2a(h0,  u2h2(za.x), aZ0); aZ1 = fdot2a(h1, u2h2(za.y), aZ1);
        aZ0 = fdot2a(h2v, u2h2(za.z), aZ0); aZ1 = fdot2a(h3, u2h2(za.w), aZ1);
        aZ0 = fdot2a(h4,  u2h2(zb.x), aZ0); aZ1 = fdot2a(h5, u2h2(zb.y), aZ1);
        aZ0 = fdot2a(h6v, u2h2(zb.z), aZ0); aZ1 = fdot2a(h7, u2h2(zb.w), aZ1);
      } else {
        int pb = (c - 3)*4;
        uint2 z0 = lw2[(pb+0)*512 + tid], z1 = lw2[(pb+1)*512 + tid];
        uint2 z2 = lw2[(pb+2)*512 + tid], z3 = lw2[(pb+3)*512 + tid];
        aZ0 = fdot2a(h0,  u2h2(z0.x), aZ0); aZ1 = fdot2a(h1, u2h2(z0.y), aZ1);
        aZ0 = fdot2a(h2v, u2h2(z1.x), aZ0); aZ1 = fdot2a(h3, u2h2(z1.y), aZ1);
        aZ0 = fdot2a(h4,  u2h2(z2.x), aZ0); aZ1 = fdot2a(h5, u2h2(z2.y), aZ1);
        aZ0 = fdot2a(h6v, u2h2(z3.x), aZ0); aZ1 = fdot2a(h7, u2h2(z3.y), aZ1);
      }
      // ---- n gate: chunks 0..3 LDS pairs (20+), 4..7 streamed uint4 ----
      if (c < 4){
        int pb = 20 + c*4;
        uint2 n0 = lw2[(pb+0)*512 + tid], n1 = lw2[(pb+1)*512 + tid];
        uint2 n2 = lw2[(pb+2)*512 + tid], n3 = lw2[(pb+3)*512 + tid];
        aN0 = fdot2a(h0,  u2h2(n0.x), aN0); aN1 = fdot2a(h1, u2h2(n0.y), aN1);
        aN0 = fdot2a(h2v, u2h2(n1.x), aN0); aN1 = fdot2a(h3, u2h2(n1.y), aN1);
        aN0 = fdot2a(h4,  u2h2(n2.x), aN0); aN1 = fdot2a(h5, u2h2(n2.y), aN1);
        aN0 = fdot2a(h6v, u2h2(n3.x), aN0); aN1 = fdot2a(h7, u2h2(n3.y), aN1);
      } else {
        uint4 na = (c == 4) ? s0 : (c == 5) ? s2 : (c == 6) ? s4 : s6;
        uint4 nb = (c == 4) ? s1 : (c == 5) ? s3 : (c == 6) ? s5 : s7;
        aN0 = fdot2a(h0,  u2h2(na.x), aN0); aN1 = fdot2a(h1, u2h2(na.y), aN1);
        aN0 = fdot2a(h2v, u2h2(na.z), aN0); aN1 = fdot2a(h3, u2h2(na.w), aN1);
        aN0 = fdot2a(h4,  u2h2(nb.x), aN0); aN1 = fdot2a(h5, u2h2(nb.y), aN1);
        aN0 = fdot2a(h6v, u2h2(nb.z), aN0); aN1 = fdot2a(h7, u2h2(nb.w), aN1);
      }
    }
    float accR = aR0 + aR1, accZ = aZ0 + aZ1, accN = aN0 + aN1;
    accR += __shfl_xor(accR, 1);
    accZ += __shfl_xor(accZ, 1);
    accN += __shfl_xor(accN, 1);
    float r = fast_sig(gxr + accR);
    float z = fast_sig(gxz + accZ);
    float n = fast_tanh(gxn + r*(accN + bN));
    float hnew = (1.f - z)*n + z*h;
    if (half == 0) hh[(t & 1) ^ 1][i] = (_Float16)hnew;
    h = hnew;
    __syncthreads();
  }

  if (half == 0) hfin[i] = h;
  __syncthreads();
  if (tid < 64){
    int r = tid >> 2, qq = tid & 3;
    const float4* wrow = (const float4*)(Wc + (size_t)r*256 + (size_t)qq*64);
    const float4* hv = (const float4*)(hfin + (size_t)qq*64);
    float acc = 0.f;
    #pragma unroll
    for (int k = 0; k < 16; k++){
      float4 wv = wrow[k];
      float4 xv = hv[k];
      acc = fmaf(wv.x, xv.x, acc);
      acc = fmaf(wv.y, xv.y, acc);
      acc = fmaf(wv.z, xv.z, acc);
      acc = fmaf(wv.w, xv.w, acc);
    }
    acc += __shfl_xor(acc, 1);
    acc += __shfl_xor(acc, 2);
    if (qq == 0) out[r] = acc + bc[r];
  }
}

extern "C" void kernel_launch(void* const* d_in, const int* in_sizes, int n_in,
                              void* d_out, int out_size, void* d_ws, size_t ws_size,
                              hipStream_t stream){
  const float* x   = (const float*)d_in[0];
  const int*   ei  = (const int*)d_in[1];
  const int*   ptr = (const int*)d_in[2];
  const float* W1  = (const float*)d_in[3];
  const float* b1  = (const float*)d_in[4];
  const float* W2  = (const float*)d_in[5];
  const float* b2  = (const float*)d_in[6];
  const float* wih = (const float*)d_in[7];
  const float* whh = (const float*)d_in[8];
  const float* bih = (const float*)d_in[9];
  const float* bhh = (const float*)d_in[10];
  const float* Wc  = (const float*)d_in[11];
  const float* bc  = (const float*)d_in[12];
  float* outp = (float*)d_out;

  const int N = in_sizes[0] / 256;   // 100000
  const int E = in_sizes[1] / 2;     // 1600000

  char* w = (char*)d_ws;
  size_t off = 0;
  auto alloc = [&](size_t bytes){ void* p = w + off; off = align512(off + bytes); return p; };
  unsigned char* bufA = (unsigned char*)alloc((size_t)N*256);     // xw (fp8 e4m3)
  ushort_t*      bufB = (ushort_t*)alloc((size_t)N*256*2);        // h  (bf16)
  float* dis  = (float*)alloc((size_t)N*4);
  int*   cnt  = (int*)  alloc((size_t)N*4);
  int*   rp   = (int*)  alloc((size_t)(N+1)*4);
  int*   bsum = (int*)  alloc(128*4);
  int*   csrc = (int*)  alloc((size_t)E*4);
  uint4* Wp1  = (uint4*)alloc(8192*16);
  uint4* Wp2  = (uint4*)alloc(8192*16);
  unsigned* whhp = (unsigned*)alloc((size_t)WHHP_TOTAL*4);        // GRU 3-tier weights
  float* hp   = (float*)alloc((size_t)64*256*4);
  float* gxb  = (float*)alloc((size_t)64*768*4);
  (void)ws_size; (void)n_in; (void)out_size;

  hipMemsetAsync(cnt, 0, (size_t)N*4, stream);
  hipMemsetAsync(hp,  0, (size_t)64*256*4, stream);

  // CSR build + degree + weight packing
  count_kernel<<<(E+255)/256, 256, 0, stream>>>(ei, cnt, E);
  dis_kernel<<<(N+255)/256, 256, 0, stream>>>(cnt, dis, N);
  int nb = (N + 1023) / 1024;
  scan_block_kernel<<<nb, 1024, 0, stream>>>(cnt, rp, bsum, N);
  scan_sums_kernel<<<1, 128, 0, stream>>>(bsum, nb);
  add_off_kernel<<<(N+255)/256, 256, 0, stream>>>(rp, bsum, cnt, N);
  fill_kernel<<<(E+255)/256, 256, 0, stream>>>(ei, rp, cnt, csrc, E);
  packW_kernel<<<32, 256, 0, stream>>>(W1, Wp1);
  packW_kernel<<<32, 256, 0, stream>>>(W2, Wp2);
  packWhh_kernel<<<384, 256, 0, stream>>>(whh, whhp);

  // GCN layer 1
  gemm_mfma<false><<<dim3((N+127)/128, 2), 256, 0, stream>>>(x, Wp1, bufA, N);
  agg_kernel<<<(N+7)/8, 256, 0, stream>>>(bufA, dis, rp, csrc, b1, bufB, N);
  // GCN layer 2
  gemm_mfma<true><<<dim3((N+127)/128, 2), 256, 0, stream>>>(bufB, Wp2, bufA, N);
  agg_kernel<<<(N+7)/8, 256, 0, stream>>>(bufA, dis, rp, csrc, b2, bufB, N);

  // pool + GRU + classifier
  pool_kernel<<<dim3(64, 8), 256, 0, stream>>>(bufB, ptr, hp);
  gx_kernel<<<64, 768, 0, stream>>>(hp, ptr, wih, bih, bhh, gxb);
  gru_kernel<<<1, 512, 0, stream>>>(gxb, whhp, bhh, Wc, bc, outp);
}

// Round 7
// 704.406 us; speedup vs baseline: 1.1910x; 1.1143x over previous
//
#include <hip/hip_runtime.h>
#include <hip/hip_bf16.h>
#include <math.h>

// Problem constants (fixed by reference): N=100000 nodes, E=1.6M edges, H=256, T=64.

static inline size_t align512(size_t x){ return (x + 511) & ~size_t(511); }

typedef _Float16 h2_t __attribute__((ext_vector_type(2)));
typedef unsigned short ushort_t;
typedef short bf16x8 __attribute__((ext_vector_type(8)));   // 8 bf16 = 4 VGPRs (MFMA A/B frag)
typedef float f32x4 __attribute__((ext_vector_type(4)));    // MFMA C/D frag
typedef float f32x2 __attribute__((ext_vector_type(2)));

#if defined(__has_builtin)
#if __has_builtin(__builtin_amdgcn_fdot2)
#define HAS_FDOT2 1
#endif
#if __has_builtin(__builtin_amdgcn_cvt_pk_f32_fp8) && __has_builtin(__builtin_amdgcn_cvt_pk_fp8_f32)
#define HAS_FP8CVT 1
#endif
#endif

__device__ inline ushort_t f2bf(float f){
  unsigned u = __float_as_uint(f);
  unsigned r = u + 0x7FFFu + ((u >> 16) & 1u);   // RTNE
  return (ushort_t)(r >> 16);
}
__device__ inline float bf2f(ushort_t h){ return __uint_as_float(((unsigned)h) << 16); }
__device__ inline unsigned pk2bf(float lo, float hi){
  return ((unsigned)f2bf(hi) << 16) | (unsigned)f2bf(lo);
}
__device__ inline bf16x8 as_bf16x8(uint4 u){
  union { uint4 u4; bf16x8 b; } c; c.u4 = u; return c.b;
}
__device__ inline h2_t u2h2(unsigned u){
  union { unsigned u; h2_t h; } c; c.u = u; return c.h;
}
__device__ inline float fdot2a(h2_t a, h2_t b, float c){
#ifdef HAS_FDOT2
  return __builtin_amdgcn_fdot2(a, b, c, false);
#else
  return fmaf((float)a.x, (float)b.x, fmaf((float)a.y, (float)b.y, c));
#endif
}

// ---- fp8 e4m3 encode/decode (HW cvt on gfx950; SW fallback approximate) ----

__device__ inline unsigned char f2fp8(float x){
#ifdef HAS_FP8CVT
  int p = __builtin_amdgcn_cvt_pk_fp8_f32(x, x, 0, false);
  return (unsigned char)(p & 0xFF);
#else
  unsigned u = __float_as_uint(x);
  unsigned s = (u >> 24) & 0x80u;
  unsigned um = u & 0x7FFFFFFFu;
  if (um >= 0x43E00000u) return (unsigned char)(s | 0x7E);      // clamp to 448
  if (um <  0x3C000000u) return (unsigned char)s;               // flush < 2^-7
  unsigned r = um + 0x7FFFFu + ((um >> 20) & 1u);               // RTNE at bit 20
  unsigned e = (r >> 23) & 0xFF, m = (r >> 20) & 7u;
  return (unsigned char)(s | ((e - 120u) << 3) | m);
#endif
}
__device__ inline void fp8x4_to_f32(unsigned v, float& a, float& b, float& c, float& d){
#ifdef HAS_FP8CVT
  f32x2 lo = __builtin_amdgcn_cvt_pk_f32_fp8(v, false);
  f32x2 hi = __builtin_amdgcn_cvt_pk_f32_fp8(v, true);
  a = lo.x; b = lo.y; c = hi.x; d = hi.y;
#else
  auto d1 = [](unsigned char t)->float{
    unsigned s = (t >> 7) & 1u, e = (t >> 3) & 0xFu, m = t & 7u;
    float v = (e == 0) ? ldexpf((float)m, -9) : ldexpf(8.0f + (float)m, (int)e - 10);
    return s ? -v : v;
  };
  a = d1(v & 0xFF); b = d1((v >> 8) & 0xFF); c = d1((v >> 16) & 0xFF); d = d1(v >> 24);
#endif
}

// ---------- CSR build ----------

__global__ void count_kernel(const int* __restrict__ ei, int* __restrict__ cnt, int E){
  int e = blockIdx.x*256 + threadIdx.x;
  if (e < E) atomicAdd(&cnt[ei[E + e]], 1);
}

__global__ void dis_kernel(const int* __restrict__ cnt, float* __restrict__ dis, int N){
  int i = blockIdx.x*256 + threadIdx.x;
  if (i < N) dis[i] = rsqrtf((float)cnt[i] + 1.0f);
}

__global__ void scan_block_kernel(const int* __restrict__ cnt, int* __restrict__ rp,
                                  int* __restrict__ bsum, int N){
  __shared__ int s[2][1024];
  int t = threadIdx.x; int i = blockIdx.x*1024 + t;
  int v = (i < N) ? cnt[i] : 0;
  int cur = 0; s[0][t] = v; __syncthreads();
  for (int off = 1; off < 1024; off <<= 1){
    int nxt = cur ^ 1;
    int val = s[cur][t];
    if (t >= off) val += s[cur][t - off];
    s[nxt][t] = val; cur = nxt; __syncthreads();
  }
  if (i < N) rp[i+1] = s[cur][t];
  if (t == 1023) bsum[blockIdx.x] = s[cur][1023];
}

__global__ void scan_sums_kernel(int* __restrict__ bsum, int nb){
  __shared__ int s[128];
  int t = threadIdx.x;
  if (t < nb) s[t] = bsum[t];
  __syncthreads();
  if (t == 0){ int acc = 0; for (int b = 0; b < nb; b++){ int v = s[b]; s[b] = acc; acc += v; } }
  __syncthreads();
  if (t < nb) bsum[t] = s[t];
}

__global__ void add_off_kernel(int* __restrict__ rp, const int* __restrict__ bsum,
                               int* __restrict__ cnt, int N){
  int i = blockIdx.x*256 + threadIdx.x;
  if (i < N){ rp[i+1] += bsum[i >> 10]; cnt[i] = 0; }
  if (i == 0) rp[0] = 0;
}

// fill: pass-major dst-range clustering. Random 4B scatters over the full
// 6.4MB csrc window caused 107MB of write amplification (measured r6:
// 113us, WRITE=107MB). 4 passes shrink the active write window to 1.6MB
// (L2-resident -> ~16 writes accumulate per line before writeback), at the
// cost of reading ei 4x coalesced (51MB ~ 9us).
#define FILL_P 4

__global__ void fill_kernel(const int* __restrict__ ei, const int* __restrict__ rp,
                            int* __restrict__ cnt, int* __restrict__ csrc, int E, int N){
  int nbp = gridDim.x / FILL_P;
  int pass = blockIdx.x / nbp;
  int blk  = blockIdx.x - pass*nbp;
  int span = (N + FILL_P - 1) / FILL_P;
  int lo = pass*span;
  int hi = min(lo + span, N);
  int e = blk*256 + threadIdx.x;
  if (e < E){
    int d = ei[E + e];
    int s = ei[e];
    if (d >= lo && d < hi){
      int pos = rp[d] + atomicAdd(&cnt[d], 1);
      csrc[pos] = s;
    }
  }
}

// ---------- pack W (256x256 fp32 [k][n]) into MFMA B-fragment order (bf16) ----------

__global__ void packW_kernel(const float* __restrict__ W, uint4* __restrict__ Wp){
  int idx = blockIdx.x*256 + threadIdx.x;    // 0..8191
  int lane = idx & 63;
  int blk  = idx >> 6;                        // 0..127
  int q    = blk & 7;
  int t16  = blk >> 3;                        // 0..15 (16-col group)
  int n = t16*16 + (lane & 15);
  int k = q*32 + (lane >> 4)*8;
  uint4 v;
  v.x = pk2bf(W[(size_t)(k+0)*256 + n], W[(size_t)(k+1)*256 + n]);
  v.y = pk2bf(W[(size_t)(k+2)*256 + n], W[(size_t)(k+3)*256 + n]);
  v.z = pk2bf(W[(size_t)(k+4)*256 + n], W[(size_t)(k+5)*256 + n]);
  v.w = pk2bf(W[(size_t)(k+6)*256 + n], W[(size_t)(k+7)*256 + n]);
  Wp[idx] = v;
}

// ---------- pack W_hh (768x256 f32) into 3-tier GRU layout (f16 h2 units) ----
// Thread t=(i,half) of the 512-thread GRU owns, per gate g in {r,z,n}, the 64
// h2 values hk = half*64 + c*8 + j (c=chunk 0..7, j=0..7) of row i+g*256.
// Tiers (per thread): REG 88 h2 = r(all 64) + z(c0..2);  LDS 72 h2 =
// z(c3..7)=40 + n(c0..3)=32;  STREAM 32 h2 = n(c4..7), replicated x2 so the
// per-step reload address alternates with t&1 (blocks LICM reg-hoisting).
// Layouts (unsigned=1 h2):  REG:  [22][512] uint4, slot s -> word s>>2, comp s&3
//                           LDS:  [36][512] uint2, item li -> pair li>>1, comp li&1
//                           STRM: [2][8][512] uint4, item si -> grp si>>2, comp si&3
#define WHHP_LBASE 45056u
#define WHHP_SBASE 81920u
#define WHHP_SREP  16384u
#define WHHP_TOTAL 114688u

__global__ void packWhh_kernel(const float* __restrict__ whh, unsigned* __restrict__ wp){
  int idx = blockIdx.x*256 + threadIdx.x;        // 0..98303
  if (idx >= 98304) return;
  int t = idx / 192;
  int m = idx - t*192;
  int i = t >> 1, half = t & 1;
  int g  = m >> 6;            // 0=r,1=z,2=n
  int mg = m & 63;
  int c = mg >> 3, j = mg & 7;
  int hk = half*64 + c*8 + j;
  int row = i + g*256;
  float a = whh[(size_t)row*256 + 2*hk];
  float b = whh[(size_t)row*256 + 2*hk + 1];
  union { _Float16 f[2]; unsigned u; } cv;
  cv.f[0] = (_Float16)a; cv.f[1] = (_Float16)b;
  if (g == 0){
    int s = c*8 + j;
    wp[(unsigned)((s >> 2)*2048 + t*4 + (s & 3))] = cv.u;
  } else if (g == 1 && c < 3){
    int s = 64 + c*8 + j;
    wp[(unsigned)((s >> 2)*2048 + t*4 + (s & 3))] = cv.u;
  } else if (g == 1){
    int li = (c-3)*8 + j;
    wp[WHHP_LBASE + (unsigned)((li >> 1)*1024 + t*2 + (li & 1))] = cv.u;
  } else if (c < 4){
    int li = 40 + c*8 + j;
    wp[WHHP_LBASE + (unsigned)((li >> 1)*1024 + t*2 + (li & 1))] = cv.u;
  } else {
    int si = (c-4)*8 + j;
    unsigned so = (unsigned)((si >> 2)*2048 + t*4 + (si & 3));
    wp[WHHP_SBASE + so] = cv.u;
    wp[WHHP_SBASE + WHHP_SREP + so] = cv.u;
  }
}

// ---------- MFMA GEMM: out[N,256](fp8 e4m3) = A[N,256] @ W[256,256] ----------
// 128x128 tile, 4 waves (2x2), each wave 64x64 via 4x4 tiles of 16x16x32 MFMA.
// B register-resident (128 VGPRs). A double-buffered in LDS. Out stored fp8
// (the consumer is the edge-gather, which is fabric-bytes-bound).

template<bool A_BF16>
__global__ __launch_bounds__(256, 2) void gemm_mfma(const void* __restrict__ Ap,
                                                    const uint4* __restrict__ Wp,
                                                    unsigned char* __restrict__ out, int N){
  __shared__ __align__(16) ushort_t As[2][128][40];
  int tid  = threadIdx.x;
  int lane = tid & 63;
  int wave = tid >> 6;
  int wr = wave >> 1, wc = wave & 1;
  int quad = lane >> 4;
  int l15  = lane & 15;
  int r0 = blockIdx.x * 128;
  int cb = blockIdx.y;

  uint4 bfr[4][8];
  {
    const uint4* wpb = Wp + (size_t)(cb*2 + wc) * 2048;
    #pragma unroll
    for (int ct = 0; ct < 4; ct++)
      #pragma unroll
      for (int q = 0; q < 8; q++)
        bfr[ct][q] = wpb[(ct*8 + q)*64 + lane];
  }

  f32x4 acc[4][4];
  #pragma unroll
  for (int rt = 0; rt < 4; rt++)
    #pragma unroll
    for (int ct = 0; ct < 4; ct++)
      acc[rt][ct] = f32x4{0.f, 0.f, 0.f, 0.f};

  int srow = tid >> 1;
  int shalf = tid & 1;
  int grow = min(r0 + srow, N - 1);

  auto load_stage = [&](int it, uint4& v0, uint4& v1){
    int k0 = it*32 + shalf*16;
    if constexpr (A_BF16){
      const ushort_t* Ab = (const ushort_t*)Ap;
      const uint4* ga = (const uint4*)(Ab + (size_t)grow*256 + k0);
      v0 = ga[0]; v1 = ga[1];
    } else {
      const float* Af = (const float*)Ap;
      const float4* ga = (const float4*)(Af + (size_t)grow*256 + k0);
      float4 f0 = ga[0], f1 = ga[1], f2 = ga[2], f3 = ga[3];
      v0.x = pk2bf(f0.x, f0.y); v0.y = pk2bf(f0.z, f0.w);
      v0.z = pk2bf(f1.x, f1.y); v0.w = pk2bf(f1.z, f1.w);
      v1.x = pk2bf(f2.x, f2.y); v1.y = pk2bf(f2.z, f2.w);
      v1.z = pk2bf(f3.x, f3.y); v1.w = pk2bf(f3.z, f3.w);
    }
  };
  auto write_stage = [&](int b, uint4 v0, uint4 v1){
    *(uint4*)&As[b][srow][shalf*16]     = v0;
    *(uint4*)&As[b][srow][shalf*16 + 8] = v1;
  };

  {
    uint4 v0, v1;
    load_stage(0, v0, v1);
    write_stage(0, v0, v1);
  }
  __syncthreads();

  #pragma unroll
  for (int it = 0; it < 8; it++){
    const int b = it & 1;
    uint4 n0, n1;
    if (it < 7) load_stage(it + 1, n0, n1);
    #pragma unroll
    for (int rt = 0; rt < 4; rt++){
      int arow = wr*64 + rt*16 + l15;
      uint4 av = *(const uint4*)&As[b][arow][quad*8];
      bf16x8 af = as_bf16x8(av);
      #pragma unroll
      for (int ct = 0; ct < 4; ct++)
        acc[rt][ct] = __builtin_amdgcn_mfma_f32_16x16x32_bf16(
            af, as_bf16x8(bfr[ct][it]), acc[rt][ct], 0, 0, 0);
    }
    if (it < 7){
      write_stage(b ^ 1, n0, n1);
      __syncthreads();
    }
  }

  // store C (fp8): row = r0+wr*64+rt*16+quad*4+g, col = cb*128+wc*64+ct*16+l15
  int crow0 = r0 + wr*64 + quad*4;
  int ccol0 = cb*128 + wc*64 + l15;
  #pragma unroll
  for (int rt = 0; rt < 4; rt++){
    #pragma unroll
    for (int g = 0; g < 4; g++){
      int row = crow0 + rt*16 + g;
      if (row < N){
        #pragma unroll
        for (int ct = 0; ct < 4; ct++)
          out[(size_t)row*256 + ccol0 + ct*16] = f2fp8(acc[rt][ct][g]);
      }
    }
  }
}

// ---------- GCN aggregation (fp8 gather -> bf16 out): half-wave (32 lanes) per
// node, 8 fp8 cols per lane as one 8B uint2 load (256B/row, fully coalesced).
// Edge loop unrolled x4 with batched index/coef loads: 4 independent 256B
// gathers in flight per half-wave (r6 showed 26% VALUBusy @ 2.3TB/s -> the
// serial dependent gather loop was latency-bound, MLP=1).

__device__ inline void acc_row8(uint2 v, float cc, float* acc){
  float v0,v1,v2,v3,v4,v5,v6,v7;
  fp8x4_to_f32(v.x, v0, v1, v2, v3);
  fp8x4_to_f32(v.y, v4, v5, v6, v7);
  acc[0] = fmaf(v0, cc, acc[0]);
  acc[1] = fmaf(v1, cc, acc[1]);
  acc[2] = fmaf(v2, cc, acc[2]);
  acc[3] = fmaf(v3, cc, acc[3]);
  acc[4] = fmaf(v4, cc, acc[4]);
  acc[5] = fmaf(v5, cc, acc[5]);
  acc[6] = fmaf(v6, cc, acc[6]);
  acc[7] = fmaf(v7, cc, acc[7]);
}

__global__ __launch_bounds__(256) void agg_kernel(const unsigned char* __restrict__ xw,
                                                  const float* __restrict__ dis,
                                                  const int* __restrict__ rp,
                                                  const int* __restrict__ csrc,
                                                  const float* __restrict__ bias,
                                                  ushort_t* __restrict__ out, int N){
  int node = blockIdx.x*8 + (threadIdx.x >> 5);
  int lane = threadIdx.x & 31;
  if (node >= N) return;
  const uint2* xw2 = (const uint2*)xw;     // 8 B = 8 fp8; row = 32 uint2
  float di = dis[node];
  float sc = di * di;
  float acc[8];
  {
    uint2 a = xw2[(size_t)node*32 + lane];
    float v0,v1,v2,v3,v4,v5,v6,v7;
    fp8x4_to_f32(a.x, v0, v1, v2, v3);
    fp8x4_to_f32(a.y, v4, v5, v6, v7);
    acc[0]=v0*sc; acc[1]=v1*sc; acc[2]=v2*sc; acc[3]=v3*sc;
    acc[4]=v4*sc; acc[5]=v5*sc; acc[6]=v6*sc; acc[7]=v7*sc;
  }
  int e0 = rp[node], e1 = rp[node+1];
  int e = e0;
  for (; e + 4 <= e1; e += 4){
    int s0 = csrc[e], s1 = csrc[e+1], s2 = csrc[e+2], s3 = csrc[e+3];
    float c0 = dis[s0]*di, c1 = dis[s1]*di, c2 = dis[s2]*di, c3 = dis[s3]*di;
    uint2 v0 = xw2[(size_t)s0*32 + lane];
    uint2 v1 = xw2[(size_t)s1*32 + lane];
    uint2 v2 = xw2[(size_t)s2*32 + lane];
    uint2 v3 = xw2[(size_t)s3*32 + lane];
    acc_row8(v0, c0, acc);
    acc_row8(v1, c1, acc);
    acc_row8(v2, c2, acc);
    acc_row8(v3, c3, acc);
  }
  for (; e < e1; e++){
    int s = csrc[e];
    float cc = dis[s] * di;
    uint2 v = xw2[(size_t)s*32 + lane];
    acc_row8(v, cc, acc);
  }
  const float4* b4 = (const float4*)bias;   // cols lane*8..lane*8+7
  float4 bA = b4[lane*2], bB = b4[lane*2+1];
  acc[0] = fmaxf(acc[0] + bA.x, 0.f);
  acc[1] = fmaxf(acc[1] + bA.y, 0.f);
  acc[2] = fmaxf(acc[2] + bA.z, 0.f);
  acc[3] = fmaxf(acc[3] + bA.w, 0.f);
  acc[4] = fmaxf(acc[4] + bB.x, 0.f);
  acc[5] = fmaxf(acc[5] + bB.y, 0.f);
  acc[6] = fmaxf(acc[6] + bB.z, 0.f);
  acc[7] = fmaxf(acc[7] + bB.w, 0.f);
  uint4 o;
  o.x = pk2bf(acc[0], acc[1]);
  o.y = pk2bf(acc[2], acc[3]);
  o.z = pk2bf(acc[4], acc[5]);
  o.w = pk2bf(acc[6], acc[7]);
  ((uint4*)out)[(size_t)node*32 + lane] = o;
}

// ---------- mean pool (bf16 input, fp32 accumulate) ----------

__global__ void pool_kernel(const ushort_t* __restrict__ h, const int* __restrict__ ptr,
                            float* __restrict__ hp){
  int t = blockIdx.x; int part = blockIdx.y; int c = threadIdx.x;
  int s0 = ptr[t], s1 = ptr[t+1];
  int len = s1 - s0;
  int chunk = (len + 7) / 8;
  int r0 = s0 + part*chunk;
  int r1 = min(r0 + chunk, s1);
  float acc = 0.f;
  for (int r = r0; r < r1; r++) acc += bf2f(h[(size_t)r*256 + c]);
  if (r1 > r0) atomicAdd(&hp[t*256 + c], acc);
}

// ---------- GX[t,g] = dot(hp[t]/cnt[t], w_ih[g]) + b_ih[g] (+ b_hh[g] for r,z
// gates, folded here so the GRU loop carries 2 fewer live VGPRs) ----------

__global__ __launch_bounds__(768) void gx_kernel(const float* __restrict__ hp,
                                                 const int* __restrict__ ptr,
                                                 const float* __restrict__ wih,
                                                 const float* __restrict__ bih,
                                                 const float* __restrict__ bhh,
                                                 float* __restrict__ gx){
  __shared__ float xs[256];
  int t = blockIdx.x; int g = threadIdx.x;
  if (g < 256){
    float cf = (float)max(ptr[t+1] - ptr[t], 1);
    xs[g] = hp[t*256 + g] / cf;
  }
  __syncthreads();
  float acc = bih[g] + (g < 512 ? bhh[g] : 0.f);
  const float* wr = wih + (size_t)g*256;
  #pragma unroll 4
  for (int k = 0; k < 256; k++) acc = fmaf(xs[k], wr[k], acc);
  gx[t*768 + g] = acc;
}

// ---------- sequential GRU: single block, 512 threads (2 threads/gate).
// 3-tier weight residency (REG 88 h2 / LDS 72 h2 / L2-stream 32 h2 per
// thread); see r6 notes. This kernel dropped out of the top-5 at r6.

__device__ inline float fast_sig(float x){
  return __builtin_amdgcn_rcpf(1.f + __expf(-x));
}
__device__ inline float fast_tanh(float x){
  // 1 - 2/(e^{2x}+1); exact limits at +-inf via rcp(inf)=0
  return 1.f - 2.f*__builtin_amdgcn_rcpf(1.f + __expf(2.f*x));
}

__global__ __launch_bounds__(512, 1) void gru_kernel(const float* __restrict__ gx,
                                                     const unsigned* __restrict__ whhp,
                                                     const float* __restrict__ bhh,
                                                     const float* __restrict__ Wc,
                                                     const float* __restrict__ bc,
                                                     float* __restrict__ out){
  __shared__ uint2 lw2[36*512];                  // 147456 B weight tier
  __shared__ __align__(16) _Float16 hh[2][256];  // 1 KB, double-buffered h
  __shared__ float hfin[256];                    // 1 KB
  int tid = threadIdx.x;
  int i = tid >> 1;        // gate index 0..255
  int half = tid & 1;      // k-half

  // register tier: 22 coalesced uint4 loads
  uint4 wreg4[22];
  {
    const uint4* R4 = (const uint4*)whhp;
    #pragma unroll
    for (int j = 0; j < 22; j++) wreg4[j] = R4[j*512 + tid];
  }
  // LDS tier: cooperative linear copy
  {
    const uint2* Lz2 = (const uint2*)(whhp + WHHP_LBASE);
    #pragma unroll
    for (int r = 0; r < 36; r++) lw2[r*512 + tid] = Lz2[r*512 + tid];
  }

  float bN = bhh[i + 512];           // r,z biases folded into gx upstream
  if (tid < 256) hh[0][tid] = (_Float16)0.f;
  float h = 0.f;
  __syncthreads();

  #pragma unroll 1
  for (int t = 0; t < 64; t++){
    const float* gxt = gx + (size_t)t*768;
    float gxr = gxt[i], gxz = gxt[256 + i], gxn = gxt[512 + i];
    const uint4* hh4 = (const uint4*)((const char*)hh + ((t & 1) << 9) + (half << 8));
    const uint4* S4 = (const uint4*)(whhp + WHHP_SBASE + ((unsigned)(t & 1))*WHHP_SREP);
    // staggered stream prefetch (peak 4 groups = 16 VGPRs in flight)
    uint4 s0 = S4[0*512 + tid], s1 = S4[1*512 + tid];
    uint4 s2, s3, s4, s5, s6, s7;
    float aR0=0.f, aR1=0.f, aZ0=0.f, aZ1=0.f, aN0=0.f, aN1=0.f;
    #pragma unroll
    for (int c = 0; c < 8; c++){
      if (c == 2){ s2 = S4[2*512 + tid]; s3 = S4[3*512 + tid]; }
      if (c == 4){ s4 = S4[4*512 + tid]; s5 = S4[5*512 + tid]; }
      if (c == 5){ s6 = S4[6*512 + tid]; s7 = S4[7*512 + tid]; }
      uint4 hA = hh4[c*2], hB = hh4[c*2 + 1];
      h2_t h0=u2h2(hA.x), h1=u2h2(hA.y), h2v=u2h2(hA.z), h3=u2h2(hA.w);
      h2_t h4=u2h2(hB.x), h5=u2h2(hB.y), h6v=u2h2(hB.z), h7=u2h2(hB.w);
      // ---- r gate: regs words 2c, 2c+1 ----
      {
        uint4 wa = wreg4[c*2], wb = wreg4[c*2 + 1];
        aR0 = fdot2a(h0,  u2h2(wa.x), aR0); aR1 = fdot2a(h1, u2h2(wa.y), aR1);
        aR0 = fdot2a(h2v, u2h2(wa.z), aR0); aR1 = fdot2a(h3, u2h2(wa.w), aR1);
        aR0 = fdot2a(h4,  u2h2(wb.x), aR0); aR1 = fdot2a(h5, u2h2(wb.y), aR1);
        aR0 = fdot2a(h6v, u2h2(wb.z), aR0); aR1 = fdot2a(h7, u2h2(wb.w), aR1);
      }
      // ---- z gate: chunks 0..2 regs (words 16+2c,17+2c), 3..7 LDS pairs ----
      if (c < 3){
        uint4 za = wreg4[16 + c*2], zb = wreg4[17 + c*2];
        aZ0 = fdot2a(h0,  u2h2(za.x), aZ0); aZ1 = fdot2a(h1, u2h2(za.y), aZ1);
        aZ0 = fdot2a(h2v, u2h2(za.z), aZ0); aZ1 = fdot2a(h3, u2h2(za.w), aZ1);
        aZ0 = fdot2a(h4,  u2h2(zb.x), aZ0); aZ1 = fdot2a(h5, u2h2(zb.y), aZ1);
        aZ0 = fdot2a(h6v, u2h2(zb.z), aZ0); aZ1 = fdot2a(h7, u2h2(zb.w), aZ1);
      } else {
        int pb = (c - 3)*4;
        uint2 z0 = lw2[(pb+0)*512 + tid], z1 = lw2[(pb+1)*512 + tid];
        uint2 z2 = lw2[(pb+2)*512 + tid], z3 = lw2[(pb+3)*512 + tid];
        aZ0 = fdot2a(h0,  u2h2(z0.x), aZ0); aZ1 = fdot2a(h1, u2h2(z0.y), aZ1);
        aZ0 = fdot2a(h2v, u2h2(z1.x), aZ0); aZ1 = fdot2a(h3, u2h2(z1.y), aZ1);
        aZ0 = fdot2a(h4,  u2h2(z2.x), aZ0); aZ1 = fdot2a(h5, u2h2(z2.y), aZ1);
        aZ0 = fdot2a(h6v, u2h2(z3.x), aZ0); aZ1 = fdot2a(h7, u2h2(z3.y), aZ1);
      }
      // ---- n gate: chunks 0..3 LDS pairs (20+), 4..7 streamed uint4 ----
      if (c < 4){
        int pb = 20 + c*4;
        uint2 n0 = lw2[(pb+0)*512 + tid], n1 = lw2[(pb+1)*512 + tid];
        uint2 n2 = lw2[(pb+2)*512 + tid], n3 = lw2[(pb+3)*512 + tid];
        aN0 = fdot2a(h0,  u2h2(n0.x), aN0); aN1 = fdot2a(h1, u2h2(n0.y), aN1);
        aN0 = fdot2a(h2v, u2h2(n1.x), aN0); aN1 = fdot2a(h3, u2h2(n1.y), aN1);
        aN0 = fdot2a(h4,  u2h2(n2.x), aN0); aN1 = fdot2a(h5, u2h2(n2.y), aN1);
        aN0 = fdot2a(h6v, u2h2(n3.x), aN0); aN1 = fdot2a(h7, u2h2(n3.y), aN1);
      } else {
        uint4 na = (c == 4) ? s0 : (c == 5) ? s2 : (c == 6) ? s4 : s6;
        uint4 nb = (c == 4) ? s1 : (c == 5) ? s3 : (c == 6) ? s5 : s7;
        aN0 = fdot2a(h0,  u2h2(na.x), aN0); aN1 = fdot2a(h1, u2h2(na.y), aN1);
        aN0 = fdot2a(h2v, u2h2(na.z), aN0); aN1 = fdot2a(h3, u2h2(na.w), aN1);
        aN0 = fdot2a(h4,  u2h2(nb.x), aN0); aN1 = fdot2a(h5, u2h2(nb.y), aN1);
        aN0 = fdot2a(h6v, u2h2(nb.z), aN0); aN1 = fdot2a(h7, u2h2(nb.w), aN1);
      }
    }
    float accR = aR0 + aR1, accZ = aZ0 + aZ1, accN = aN0 + aN1;
    accR += __shfl_xor(accR, 1);
    accZ += __shfl_xor(accZ, 1);
    accN += __shfl_xor(accN, 1);
    float r = fast_sig(gxr + accR);
    float z = fast_sig(gxz + accZ);
    float n = fast_tanh(gxn + r*(accN + bN));
    float hnew = (1.f - z)*n + z*h;
    if (half == 0) hh[(t & 1) ^ 1][i] = (_Float16)hnew;
    h = hnew;
    __syncthreads();
  }

  if (half == 0) hfin[i] = h;
  __syncthreads();
  if (tid < 64){
    int r = tid >> 2, qq = tid & 3;
    const float4* wrow = (const float4*)(Wc + (size_t)r*256 + (size_t)qq*64);
    const float4* hv = (const float4*)(hfin + (size_t)qq*64);
    float acc = 0.f;
    #pragma unroll
    for (int k = 0; k < 16; k++){
      float4 wv = wrow[k];
      float4 xv = hv[k];
      acc = fmaf(wv.x, xv.x, acc);
      acc = fmaf(wv.y, xv.y, acc);
      acc = fmaf(wv.z, xv.z, acc);
      acc = fmaf(wv.w, xv.w, acc);
    }
    acc += __shfl_xor(acc, 1);
    acc += __shfl_xor(acc, 2);
    if (qq == 0) out[r] = acc + bc[r];
  }
}

extern "C" void kernel_launch(void* const* d_in, const int* in_sizes, int n_in,
                              void* d_out, int out_size, void* d_ws, size_t ws_size,
                              hipStream_t stream){
  const float* x   = (const float*)d_in[0];
  const int*   ei  = (const int*)d_in[1];
  const int*   ptr = (const int*)d_in[2];
  const float* W1  = (const float*)d_in[3];
  const float* b1  = (const float*)d_in[4];
  const float* W2  = (const float*)d_in[5];
  const float* b2  = (const float*)d_in[6];
  const float* wih = (const float*)d_in[7];
  const float* whh = (const float*)d_in[8];
  const float* bih = (const float*)d_in[9];
  const float* bhh = (const float*)d_in[10];
  const float* Wc  = (const float*)d_in[11];
  const float* bc  = (const float*)d_in[12];
  float* outp = (float*)d_out;

  const int N = in_sizes[0] / 256;   // 100000
  const int E = in_sizes[1] / 2;     // 1600000

  char* w = (char*)d_ws;
  size_t off = 0;
  auto alloc = [&](size_t bytes){ void* p = w + off; off = align512(off + bytes); return p; };
  unsigned char* bufA = (unsigned char*)alloc((size_t)N*256);     // xw (fp8 e4m3)
  ushort_t*      bufB = (ushort_t*)alloc((size_t)N*256*2);        // h  (bf16)
  float* dis  = (float*)alloc((size_t)N*4);
  int*   cnt  = (int*)  alloc((size_t)N*4);
  int*   rp   = (int*)  alloc((size_t)(N+1)*4);
  int*   bsum = (int*)  alloc(128*4);
  int*   csrc = (int*)  alloc((size_t)E*4);
  uint4* Wp1  = (uint4*)alloc(8192*16);
  uint4* Wp2  = (uint4*)alloc(8192*16);
  unsigned* whhp = (unsigned*)alloc((size_t)WHHP_TOTAL*4);        // GRU 3-tier weights
  float* hp   = (float*)alloc((size_t)64*256*4);
  float* gxb  = (float*)alloc((size_t)64*768*4);
  (void)ws_size; (void)n_in; (void)out_size;

  hipMemsetAsync(cnt, 0, (size_t)N*4, stream);
  hipMemsetAsync(hp,  0, (size_t)64*256*4, stream);

  // CSR build + degree + weight packing
  count_kernel<<<(E+255)/256, 256, 0, stream>>>(ei, cnt, E);
  dis_kernel<<<(N+255)/256, 256, 0, stream>>>(cnt, dis, N);
  int nb = (N + 1023) / 1024;
  scan_block_kernel<<<nb, 1024, 0, stream>>>(cnt, rp, bsum, N);
  scan_sums_kernel<<<1, 128, 0, stream>>>(bsum, nb);
  add_off_kernel<<<(N+255)/256, 256, 0, stream>>>(rp, bsum, cnt, N);
  int fnb = (E + 255) / 256;
  fill_kernel<<<fnb*FILL_P, 256, 0, stream>>>(ei, rp, cnt, csrc, E, N);
  packW_kernel<<<32, 256, 0, stream>>>(W1, Wp1);
  packW_kernel<<<32, 256, 0, stream>>>(W2, Wp2);
  packWhh_kernel<<<384, 256, 0, stream>>>(whh, whhp);

  // GCN layer 1
  gemm_mfma<false><<<dim3((N+127)/128, 2), 256, 0, stream>>>(x, Wp1, bufA, N);
  agg_kernel<<<(N+7)/8, 256, 0, stream>>>(bufA, dis, rp, csrc, b1, bufB, N);
  // GCN layer 2
  gemm_mfma<true><<<dim3((N+127)/128, 2), 256, 0, stream>>>(bufB, Wp2, bufA, N);
  agg_kernel<<<(N+7)/8, 256, 0, stream>>>(bufA, dis, rp, csrc, b2, bufB, N);

  // pool + GRU + classifier
  pool_kernel<<<dim3(64, 8), 256, 0, stream>>>(bufB, ptr, hp);
  gx_kernel<<<64, 768, 0, stream>>>(hp, ptr, wih, bih, bhh, gxb);
  gru_kernel<<<1, 512, 0, stream>>>(gxb, whhp, bhh, Wc, bc, outp);
}